// Round 2
// baseline (2798.791 us; speedup 1.0000x reference)
//
#include <hip/hip_runtime.h>
#include <hip/hip_bf16.h>

#define T_FRAMES 64

// ---------------------------------------------------------------------------
// de_layers[0]: x0[t, j] = latent[t,:] . W0[j,:] + b0[j]   (j < 2560 = 20*128)
// ---------------------------------------------------------------------------
__global__ __launch_bounds__(256) void linear0_kernel(
    const float* __restrict__ latent, const float* __restrict__ W0,
    const float* __restrict__ b0, float* __restrict__ out) {
  int id = blockIdx.x * 256 + threadIdx.x;
  if (id >= 64 * 2560) return;
  int j = id % 2560;
  int t = id / 2560;
  const float* lrow = latent + t * 128;
  const float* wrow = W0 + j * 128;
  float acc = b0[j];
#pragma unroll 8
  for (int k = 0; k < 128; ++k) acc = fmaf(lrow[k], wrow[k], acc);
  out[id] = acc;  // [t][20][128] row-major
}

// ---------------------------------------------------------------------------
// pool: out[:, rows[e], :] += x[:, cols[e], :] * vals[e]  (atomic scatter-add)
// thread = (e, t, c) with c fastest -> coalesced, e/t wave-uniform (C>=64)
// ---------------------------------------------------------------------------
template <int C>
__global__ __launch_bounds__(256) void pool_kernel(
    const float* __restrict__ x, const int* __restrict__ rows,
    const int* __restrict__ cols, const float* __restrict__ vals,
    float* __restrict__ out, int nnz, int n_in, int n_out) {
  unsigned id = blockIdx.x * 256u + threadIdx.x;
  unsigned total = (unsigned)nnz * T_FRAMES * C;
  if (id >= total) return;
  int c = id % C;
  int t = (id / C) % T_FRAMES;
  int e = id / (C * T_FRAMES);
  float v = x[(t * n_in + cols[e]) * C + c] * vals[e];
  atomicAdd(&out[(t * n_out + rows[e]) * C + c], v);
}

// ---------------------------------------------------------------------------
// spiral conv: out[t,v,co] = ELU( sum_{s,ci} x[t, idx[v,s], ci] * W[co, s*CIN+ci] + b[co] )
// Block: one frame t x VT vertices. Gathered rows staged in LDS.
// Threads: (c_out fastest, vertex-group) -> LDS reads wave-uniform (broadcast),
// W reads stream per-lane float4, ACC vertices per thread reuse each W element.
// ---------------------------------------------------------------------------
template <int CIN, int COUT, int VT, bool DOELU>
__global__ __launch_bounds__(256) void spiral_conv_kernel(
    const float* __restrict__ x, const int* __restrict__ idx,
    const float* __restrict__ W, const float* __restrict__ bias,
    float* __restrict__ out, int n) {
  constexpr int K = 9 * CIN;
  constexpr int LDK = K + 4;               // pad keeps 16B alignment, kills conflicts
  constexpr int ACC = (VT * COUT) / 256;   // vertices per thread
  __shared__ float g[VT][LDK];

  const int t = blockIdx.y;
  const int v0 = blockIdx.x * VT;
  const int tid = threadIdx.x;

  // ---- stage gathered spiral rows into LDS ----
  for (int u = tid; u < VT * K; u += 256) {
    int vl = u / K;
    int k = u - vl * K;
    int v = v0 + vl;
    if (v < n) {
      int s = k / CIN;
      int ci = k - s * CIN;
      int vid = idx[v * 9 + s];
      g[vl][k] = x[(t * n + vid) * CIN + ci];
    }
  }
  __syncthreads();

  const int c = tid % COUT;
  const int vg = tid / COUT;
  float acc[ACC];
#pragma unroll
  for (int i = 0; i < ACC; ++i) acc[i] = bias[c];

  const float* wrow = W + c * K;
  for (int k = 0; k < K; k += 4) {
    const float4 wv = *(const float4*)(wrow + k);
#pragma unroll
    for (int i = 0; i < ACC; ++i) {
      const float4 xv = *(const float4*)(&g[vg * ACC + i][k]);
      acc[i] = fmaf(xv.x, wv.x, fmaf(xv.y, wv.y, fmaf(xv.z, wv.z, fmaf(xv.w, wv.w, acc[i]))));
    }
  }

#pragma unroll
  for (int i = 0; i < ACC; ++i) {
    int v = v0 + vg * ACC + i;
    if (v < n) {
      float a = acc[i];
      if (DOELU) a = a > 0.f ? a : expm1f(a);
      out[(t * n + v) * COUT + c] = a;
    }
  }
}

// ---------------------------------------------------------------------------
// final conv 32 -> 3 (+ actor):  thread = (t, v), K = 288, Wf tiny (L1-resident)
// ---------------------------------------------------------------------------
__global__ __launch_bounds__(256) void final_conv_kernel(
    const float* __restrict__ x, const int* __restrict__ idx,
    const float* __restrict__ Wf, const float* __restrict__ bf,
    const float* __restrict__ actor, float* __restrict__ out) {
  int id = blockIdx.x * 256 + threadIdx.x;
  if (id >= 64 * 5023) return;
  int v = id % 5023;
  int t = id / 5023;
  float a0 = bf[0], a1 = bf[1], a2 = bf[2];
  for (int s = 0; s < 9; ++s) {
    int vid = idx[v * 9 + s];
    const float* xp = x + (t * 5023 + vid) * 32;
    const float* w0 = Wf + s * 32;         // row c=0
    const float* w1 = Wf + 288 + s * 32;   // row c=1
    const float* w2 = Wf + 576 + s * 32;   // row c=2
#pragma unroll
    for (int ci = 0; ci < 32; ci += 4) {
      const float4 xv = *(const float4*)(xp + ci);
      const float4 wa = *(const float4*)(w0 + ci);
      const float4 wb = *(const float4*)(w1 + ci);
      const float4 wc = *(const float4*)(w2 + ci);
      a0 = fmaf(xv.x, wa.x, fmaf(xv.y, wa.y, fmaf(xv.z, wa.z, fmaf(xv.w, wa.w, a0))));
      a1 = fmaf(xv.x, wb.x, fmaf(xv.y, wb.y, fmaf(xv.z, wb.z, fmaf(xv.w, wb.w, a1))));
      a2 = fmaf(xv.x, wc.x, fmaf(xv.y, wc.y, fmaf(xv.z, wc.z, fmaf(xv.w, wc.w, a2))));
    }
  }
  float* op = out + (t * 5023 + v) * 3;
  op[0] = a0 + actor[v * 3 + 0];
  op[1] = a1 + actor[v * 3 + 1];
  op[2] = a2 + actor[v * 3 + 2];
}

// ---------------------------------------------------------------------------
extern "C" void kernel_launch(void* const* d_in, const int* in_sizes, int n_in_args,
                              void* d_out, int out_size, void* d_ws, size_t ws_size,
                              hipStream_t stream) {
  const float* latent = (const float*)d_in[0];
  const float* actor  = (const float*)d_in[1];
  const int* spiral0 = (const int*)d_in[2];
  const int* spiral1 = (const int*)d_in[3];
  const int* spiral2 = (const int*)d_in[4];
  const int* spiral3 = (const int*)d_in[5];
  const int* up0_rows = (const int*)d_in[6];
  const int* up0_cols = (const int*)d_in[7];
  const float* up0_vals = (const float*)d_in[8];
  const int* up1_rows = (const int*)d_in[9];
  const int* up1_cols = (const int*)d_in[10];
  const float* up1_vals = (const float*)d_in[11];
  const int* up2_rows = (const int*)d_in[12];
  const int* up2_cols = (const int*)d_in[13];
  const float* up2_vals = (const float*)d_in[14];
  const int* up3_rows = (const int*)d_in[15];
  const int* up3_cols = (const int*)d_in[16];
  const float* up3_vals = (const float*)d_in[17];
  const float* W0 = (const float*)d_in[18];
  const float* b0 = (const float*)d_in[19];
  const float* W1 = (const float*)d_in[20];
  const float* b1 = (const float*)d_in[21];
  const float* W2 = (const float*)d_in[22];
  const float* b2 = (const float*)d_in[23];
  const float* W3 = (const float*)d_in[24];
  const float* b3 = (const float*)d_in[25];
  const float* W4 = (const float*)d_in[26];
  const float* b4 = (const float*)d_in[27];
  const float* Wf = (const float*)d_in[28];
  const float* bf = (const float*)d_in[29];
  float* out = (float*)d_out;

  // workspace: poolbuf (max 64*5023*64 fl = 82.3MB) | convbuf (max 64*5023*32 fl = 41.1MB)
  float* poolbuf = (float*)d_ws;
  float* convbuf = poolbuf + 20574208;

  // ---- dense: latent -> [64,20,128] (into convbuf) ----
  linear0_kernel<<<(64 * 2560 + 255) / 256, 256, 0, stream>>>(latent, W0, b0, convbuf);

  // ---- level 3: pool 20->79 (C=128), conv 128->128 ----
  hipMemsetAsync(poolbuf, 0, (size_t)64 * 79 * 128 * 4, stream);
  {
    int nnz = 237, tot = nnz * 64 * 128;
    pool_kernel<128><<<(tot + 255) / 256, 256, 0, stream>>>(
        convbuf, up3_rows, up3_cols, up3_vals, poolbuf, nnz, 20, 79);
  }
  spiral_conv_kernel<128, 128, 8, true><<<dim3((79 + 7) / 8, 64), 256, 0, stream>>>(
      poolbuf, spiral3, W1, b1, convbuf, 79);

  // ---- level 2: pool 79->314 (C=128), conv 128->64 ----
  hipMemsetAsync(poolbuf, 0, (size_t)64 * 314 * 128 * 4, stream);
  {
    int nnz = 942, tot = nnz * 64 * 128;
    pool_kernel<128><<<(tot + 255) / 256, 256, 0, stream>>>(
        convbuf, up2_rows, up2_cols, up2_vals, poolbuf, nnz, 79, 314);
  }
  spiral_conv_kernel<128, 64, 8, true><<<dim3((314 + 7) / 8, 64), 256, 0, stream>>>(
      poolbuf, spiral2, W2, b2, convbuf, 314);

  // ---- level 1: pool 314->1256 (C=64), conv 64->64 ----
  hipMemsetAsync(poolbuf, 0, (size_t)64 * 1256 * 64 * 4, stream);
  {
    int nnz = 3768, tot = nnz * 64 * 64;
    pool_kernel<64><<<(tot + 255) / 256, 256, 0, stream>>>(
        convbuf, up1_rows, up1_cols, up1_vals, poolbuf, nnz, 314, 1256);
  }
  spiral_conv_kernel<64, 64, 16, true><<<dim3((1256 + 15) / 16, 64), 256, 0, stream>>>(
      poolbuf, spiral1, W3, b3, convbuf, 1256);

  // ---- level 0: pool 1256->5023 (C=64), conv 64->32 ----
  hipMemsetAsync(poolbuf, 0, (size_t)64 * 5023 * 64 * 4, stream);
  {
    int nnz = 15069;
    unsigned tot = (unsigned)nnz * 64 * 64;
    pool_kernel<64><<<(tot + 255) / 256, 256, 0, stream>>>(
        convbuf, up0_rows, up0_cols, up0_vals, poolbuf, nnz, 1256, 5023);
  }
  spiral_conv_kernel<64, 32, 16, true><<<dim3((5023 + 15) / 16, 64), 256, 0, stream>>>(
      poolbuf, spiral0, W4, b4, convbuf, 5023);

  // ---- final conv 32->3 + actor ----
  final_conv_kernel<<<(64 * 5023 + 255) / 256, 256, 0, stream>>>(
      convbuf, spiral0, Wf, bf, actor, out);
}

// Round 3
// 825.996 us; speedup vs baseline: 3.3884x; 3.3884x over previous
//
#include <hip/hip_runtime.h>
#include <hip/hip_bf16.h>

#define T_FRAMES 64

typedef __bf16 bf16x8 __attribute__((ext_vector_type(8)));
typedef float f32x4 __attribute__((ext_vector_type(4)));

// ---------------------------------------------------------------------------
// de_layers[0]: x0[t, j] = latent[t,:] . W0[j,:] + b0[j]  -> bf16 out
// ---------------------------------------------------------------------------
__global__ __launch_bounds__(256) void linear0_kernel(
    const float* __restrict__ latent, const float* __restrict__ W0,
    const float* __restrict__ b0, __bf16* __restrict__ out) {
  int id = blockIdx.x * 256 + threadIdx.x;
  if (id >= 64 * 2560) return;
  int j = id % 2560;
  int t = id / 2560;
  const float* lrow = latent + t * 128;
  const float* wrow = W0 + j * 128;
  float acc = b0[j];
#pragma unroll 8
  for (int k = 0; k < 128; ++k) acc = fmaf(lrow[k], wrow[k], acc);
  out[id] = (__bf16)acc;
}

// ---------------------------------------------------------------------------
// weight fp32 -> bf16
// ---------------------------------------------------------------------------
__global__ __launch_bounds__(256) void cvt_w_kernel(const float* __restrict__ w,
                                                    __bf16* __restrict__ o, int nelem) {
  int i = blockIdx.x * 256 + threadIdx.x;
  if (i < nelem) o[i] = (__bf16)w[i];
}

// final weight 3x288 -> padded 16x288 bf16 (rows 3..15 zero)
__global__ __launch_bounds__(256) void cvt_wf_kernel(const float* __restrict__ wf,
                                                     __bf16* __restrict__ o) {
  int i = blockIdx.x * 256 + threadIdx.x;
  if (i >= 16 * 288) return;
  int co = i / 288;
  o[i] = (co < 3) ? (__bf16)wf[i] : (__bf16)0.f;
}

// ---------------------------------------------------------------------------
// pool: out[:, rows[e], :] += x[:, cols[e], :] * vals[e]  (atomic scatter-add)
// x bf16, out fp32
// ---------------------------------------------------------------------------
template <int C>
__global__ __launch_bounds__(256) void pool_kernel(
    const __bf16* __restrict__ x, const int* __restrict__ rows,
    const int* __restrict__ cols, const float* __restrict__ vals,
    float* __restrict__ out, int nnz, int n_in, int n_out) {
  unsigned id = blockIdx.x * 256u + threadIdx.x;
  unsigned total = (unsigned)nnz * T_FRAMES * C;
  if (id >= total) return;
  int c = id % C;
  int t = (id / C) % T_FRAMES;
  int e = id / (C * T_FRAMES);
  float v = (float)x[(t * n_in + cols[e]) * C + c] * vals[e];
  atomicAdd(&out[(t * n_out + rows[e]) * C + c], v);
}

// ---------------------------------------------------------------------------
// spiral conv as bf16 MFMA GEMM.  A[m,k] = x[t, idx[v, k/CIN], k%CIN], m=t*n+v
// W (bf16) is [COUT][K] row-major = B^T; D = A.B via mfma_f32_16x16x32_bf16.
// One wave per 16-row M-tile; M = 64n ≡ 0 mod 16, grid = n blocks of 4 waves.
// A-frag: lane holds 8 contiguous k of row m0+(lane&15), kgroup=(lane>>4).
// x read as fp32 (pool buffer), converted in-register.
// ---------------------------------------------------------------------------
template <int CIN, int COUT>
__global__ __launch_bounds__(256) void conv_mfma_kernel(
    const float* __restrict__ x, const int* __restrict__ idx,
    const __bf16* __restrict__ Wb, const float* __restrict__ bias,
    __bf16* __restrict__ out, int n) {
  constexpr int K = 9 * CIN;
  constexpr int KK = K / 32;
  constexpr int NT = COUT / 16;

  const int lane = threadIdx.x & 63;
  const int wid = threadIdx.x >> 6;
  const int mtile = blockIdx.x * 4 + wid;
  const int col = lane & 15;
  const int kg = lane >> 4;

  const int m = mtile * 16 + col;   // gather row for A-frag
  const int t = m / n;
  const int v = m - t * n;

  int base[9];
#pragma unroll
  for (int s = 0; s < 9; ++s) base[s] = (t * n + idx[v * 9 + s]) * CIN;

  f32x4 acc[NT];
#pragma unroll
  for (int nt = 0; nt < NT; ++nt) {
    float b = bias[nt * 16 + col];
    acc[nt] = (f32x4){b, b, b, b};
  }

#pragma unroll
  for (int kk = 0; kk < KK; ++kk) {
    const int k0 = kk * 32 + kg * 8;
    const int s = k0 / CIN;        // compile-time after unroll
    const int ci = k0 - s * CIN;
    const float* xp = x + base[s] + ci;
    f32x4 lo = *(const f32x4*)xp;
    f32x4 hi = *(const f32x4*)(xp + 4);
    bf16x8 a;
    a[0] = (__bf16)lo[0]; a[1] = (__bf16)lo[1]; a[2] = (__bf16)lo[2]; a[3] = (__bf16)lo[3];
    a[4] = (__bf16)hi[0]; a[5] = (__bf16)hi[1]; a[6] = (__bf16)hi[2]; a[7] = (__bf16)hi[3];
#pragma unroll
    for (int nt = 0; nt < NT; ++nt) {
      bf16x8 bfr = *(const bf16x8*)(Wb + (size_t)(nt * 16 + col) * K + k0);
      acc[nt] = __builtin_amdgcn_mfma_f32_16x16x32_bf16(a, bfr, acc[nt], 0, 0, 0);
    }
  }

  // D: col = lane&15 (=cout within tile), row = kg*4 + j  -> flat m index
#pragma unroll
  for (int j = 0; j < 4; ++j) {
    const int mr = mtile * 16 + kg * 4 + j;
#pragma unroll
    for (int nt = 0; nt < NT; ++nt) {
      float aa = acc[nt][j];
      aa = aa > 0.f ? aa : expm1f(aa);   // ELU
      out[(size_t)mr * COUT + nt * 16 + col] = (__bf16)aa;
    }
  }
}

// ---------------------------------------------------------------------------
// final conv 32->3 (+actor) as MFMA with N padded to 16. x bf16, out fp32.
// ---------------------------------------------------------------------------
__global__ __launch_bounds__(256) void final_mfma_kernel(
    const __bf16* __restrict__ x, const int* __restrict__ idx,
    const __bf16* __restrict__ Wfp, const float* __restrict__ bf3,
    const float* __restrict__ actor, float* __restrict__ out) {
  constexpr int n = 5023;
  const int lane = threadIdx.x & 63;
  const int wid = threadIdx.x >> 6;
  const int mtile = blockIdx.x * 4 + wid;
  const int col = lane & 15;
  const int kg = lane >> 4;

  const int m = mtile * 16 + col;
  const int t = m / n;
  const int v = m - t * n;

  int base[9];
#pragma unroll
  for (int s = 0; s < 9; ++s) base[s] = (t * n + idx[v * 9 + s]) * 32;

  float b = (col < 3) ? bf3[col] : 0.f;
  f32x4 acc = (f32x4){b, b, b, b};

#pragma unroll
  for (int kk = 0; kk < 9; ++kk) {
    bf16x8 a = *(const bf16x8*)(x + base[kk] + kg * 8);
    bf16x8 w = *(const bf16x8*)(Wfp + col * 288 + kk * 32 + kg * 8);
    acc = __builtin_amdgcn_mfma_f32_16x16x32_bf16(a, w, acc, 0, 0, 0);
  }

  if (col < 3) {
#pragma unroll
    for (int j = 0; j < 4; ++j) {
      const int mr = mtile * 16 + kg * 4 + j;
      const int vr = mr % n;
      out[(size_t)mr * 3 + col] = acc[j] + actor[vr * 3 + col];
    }
  }
}

// ---------------------------------------------------------------------------
extern "C" void kernel_launch(void* const* d_in, const int* in_sizes, int n_in_args,
                              void* d_out, int out_size, void* d_ws, size_t ws_size,
                              hipStream_t stream) {
  const float* latent = (const float*)d_in[0];
  const float* actor  = (const float*)d_in[1];
  const int* spiral0 = (const int*)d_in[2];
  const int* spiral1 = (const int*)d_in[3];
  const int* spiral2 = (const int*)d_in[4];
  const int* spiral3 = (const int*)d_in[5];
  const int* up0_rows = (const int*)d_in[6];
  const int* up0_cols = (const int*)d_in[7];
  const float* up0_vals = (const float*)d_in[8];
  const int* up1_rows = (const int*)d_in[9];
  const int* up1_cols = (const int*)d_in[10];
  const float* up1_vals = (const float*)d_in[11];
  const int* up2_rows = (const int*)d_in[12];
  const int* up2_cols = (const int*)d_in[13];
  const float* up2_vals = (const float*)d_in[14];
  const int* up3_rows = (const int*)d_in[15];
  const int* up3_cols = (const int*)d_in[16];
  const float* up3_vals = (const float*)d_in[17];
  const float* W0 = (const float*)d_in[18];
  const float* b0 = (const float*)d_in[19];
  const float* W1 = (const float*)d_in[20];
  const float* b1 = (const float*)d_in[21];
  const float* W2 = (const float*)d_in[22];
  const float* b2 = (const float*)d_in[23];
  const float* W3 = (const float*)d_in[24];
  const float* b3 = (const float*)d_in[25];
  const float* W4 = (const float*)d_in[26];
  const float* b4 = (const float*)d_in[27];
  const float* Wf = (const float*)d_in[28];
  const float* bf3 = (const float*)d_in[29];
  float* out = (float*)d_out;

  // ---- workspace layout (103.4 MB total; 123 MB proven safe) ----
  // poolbuf f32: 20,574,208 floats (82.3 MB)
  // convout bf16: 10,287,104 elems (20.6 MB)
  // wbuf bf16: 281,088 elems (0.56 MB)
  float* poolbuf = (float*)d_ws;
  __bf16* convout = (__bf16*)(poolbuf + 20574208);
  __bf16* wbuf = convout + 10287104;
  __bf16* W1b = wbuf;                 // 128*1152
  __bf16* W2b = W1b + 147456;         // 64*1152
  __bf16* W3b = W2b + 73728;          // 64*576
  __bf16* W4b = W3b + 36864;          // 32*576
  __bf16* Wfp = W4b + 18432;          // 16*288 (zero-padded)

  // ---- convert weights to bf16 ----
  cvt_w_kernel<<<(147456 + 255) / 256, 256, 0, stream>>>(W1, W1b, 147456);
  cvt_w_kernel<<<(73728 + 255) / 256, 256, 0, stream>>>(W2, W2b, 73728);
  cvt_w_kernel<<<(36864 + 255) / 256, 256, 0, stream>>>(W3, W3b, 36864);
  cvt_w_kernel<<<(18432 + 255) / 256, 256, 0, stream>>>(W4, W4b, 18432);
  cvt_wf_kernel<<<(16 * 288 + 255) / 256, 256, 0, stream>>>(Wf, Wfp);

  // ---- dense: latent -> [64,20,128] bf16 ----
  linear0_kernel<<<(64 * 2560 + 255) / 256, 256, 0, stream>>>(latent, W0, b0, convout);

  // ---- level 3: pool 20->79 (C=128), conv 128->128 ----
  hipMemsetAsync(poolbuf, 0, (size_t)64 * 79 * 128 * 4, stream);
  pool_kernel<128><<<(237 * 64 * 128 + 255) / 256, 256, 0, stream>>>(
      convout, up3_rows, up3_cols, up3_vals, poolbuf, 237, 20, 79);
  conv_mfma_kernel<128, 128><<<79, 256, 0, stream>>>(poolbuf, spiral3, W1b, b1, convout, 79);

  // ---- level 2: pool 79->314 (C=128), conv 128->64 ----
  hipMemsetAsync(poolbuf, 0, (size_t)64 * 314 * 128 * 4, stream);
  pool_kernel<128><<<(942 * 64 * 128 + 255) / 256, 256, 0, stream>>>(
      convout, up2_rows, up2_cols, up2_vals, poolbuf, 942, 79, 314);
  conv_mfma_kernel<128, 64><<<314, 256, 0, stream>>>(poolbuf, spiral2, W2b, b2, convout, 314);

  // ---- level 1: pool 314->1256 (C=64), conv 64->64 ----
  hipMemsetAsync(poolbuf, 0, (size_t)64 * 1256 * 64 * 4, stream);
  pool_kernel<64><<<(3768 * 64 * 64 + 255) / 256, 256, 0, stream>>>(
      convout, up1_rows, up1_cols, up1_vals, poolbuf, 3768, 314, 1256);
  conv_mfma_kernel<64, 64><<<1256, 256, 0, stream>>>(poolbuf, spiral1, W3b, b3, convout, 1256);

  // ---- level 0: pool 1256->5023 (C=64), conv 64->32 ----
  hipMemsetAsync(poolbuf, 0, (size_t)64 * 5023 * 64 * 4, stream);
  {
    unsigned tot = 15069u * 64 * 64;
    pool_kernel<64><<<(tot + 255) / 256, 256, 0, stream>>>(
        convout, up0_rows, up0_cols, up0_vals, poolbuf, 15069, 1256, 5023);
  }
  conv_mfma_kernel<64, 32><<<5023, 256, 0, stream>>>(poolbuf, spiral0, W4b, b4, convout, 5023);

  // ---- final conv 32->3 + actor (MFMA, N padded to 16) ----
  final_mfma_kernel<<<5023, 256, 0, stream>>>(convout, spiral0, Wfp, bf3, actor, out);
}

// Round 4
// 635.059 us; speedup vs baseline: 4.4071x; 1.3007x over previous
//
#include <hip/hip_runtime.h>
#include <hip/hip_bf16.h>

#define T_FRAMES 64

typedef __bf16 bf16x8 __attribute__((ext_vector_type(8)));
typedef float f32x4 __attribute__((ext_vector_type(4)));

// edge counts per level (fine->coarse): nnz = 3 * n_fine
#define NNZ0 15069
#define NNZ1 3768
#define NNZ2 942
#define NNZ3 237
#define N0 5023
#define N1 1256
#define N2 314
#define N3 79
#define N4 20

// ---------------------------------------------------------------------------
// de_layers[0]: x0[t, j] = latent[t,:] . W0[j,:] + b0[j]  -> bf16 out
// ---------------------------------------------------------------------------
__global__ __launch_bounds__(256) void linear0_kernel(
    const float* __restrict__ latent, const float* __restrict__ W0,
    const float* __restrict__ b0, __bf16* __restrict__ out) {
  int id = blockIdx.x * 256 + threadIdx.x;
  if (id >= 64 * 2560) return;
  int j = id % 2560;
  int t = id / 2560;
  const float* lrow = latent + t * 128;
  const float* wrow = W0 + j * 128;
  float acc = b0[j];
#pragma unroll 8
  for (int k = 0; k < 128; ++k) acc = fmaf(lrow[k], wrow[k], acc);
  out[id] = (__bf16)acc;
}

// ---------------------------------------------------------------------------
// all weights fp32 -> bf16 in one kernel (wbuf is contiguous; Wf zero-padded
// from 3x288 to 16x288)
// ---------------------------------------------------------------------------
__global__ __launch_bounds__(256) void cvt_all_kernel(
    const float* __restrict__ W1, const float* __restrict__ W2,
    const float* __restrict__ W3, const float* __restrict__ W4,
    const float* __restrict__ Wf, __bf16* __restrict__ o) {
  int i = blockIdx.x * 256 + threadIdx.x;
  if (i < 147456) { o[i] = (__bf16)W1[i]; return; }
  if (i < 221184) { o[i] = (__bf16)W2[i - 147456]; return; }
  if (i < 258048) { o[i] = (__bf16)W3[i - 221184]; return; }
  if (i < 276480) { o[i] = (__bf16)W4[i - 258048]; return; }
  if (i < 281088) {
    int j = i - 276480;
    o[i] = (j / 288 < 3) ? (__bf16)Wf[j] : (__bf16)0.f;
  }
}

// ---------------------------------------------------------------------------
// CSR build: count -> scan (per-level block) -> bucket fill
// ---------------------------------------------------------------------------
__global__ __launch_bounds__(256) void csr_count_kernel(
    const int* __restrict__ r0, const int* __restrict__ r1,
    const int* __restrict__ r2, const int* __restrict__ r3,
    int* __restrict__ c0, int* __restrict__ c1,
    int* __restrict__ c2, int* __restrict__ c3) {
  int i = blockIdx.x * 256 + threadIdx.x;
  if (i < NNZ0) atomicAdd(&c0[r0[i]], 1);
  else if (i < NNZ0 + NNZ1) atomicAdd(&c1[r1[i - NNZ0]], 1);
  else if (i < NNZ0 + NNZ1 + NNZ2) atomicAdd(&c2[r2[i - NNZ0 - NNZ1]], 1);
  else if (i < NNZ0 + NNZ1 + NNZ2 + NNZ3) atomicAdd(&c3[r3[i - NNZ0 - NNZ1 - NNZ2]], 1);
}

// block b scans level b: counts -> exclusive offsets (+total at [n]) + cursor copy
__global__ __launch_bounds__(256) void csr_scan_kernel(
    const int* __restrict__ c0, const int* __restrict__ c1,
    const int* __restrict__ c2, const int* __restrict__ c3,
    int* __restrict__ o0, int* __restrict__ o1,
    int* __restrict__ o2, int* __restrict__ o3,
    int* __restrict__ u0, int* __restrict__ u1,
    int* __restrict__ u2, int* __restrict__ u3) {
  const int b = blockIdx.x;
  const int* counts = b == 0 ? c0 : b == 1 ? c1 : b == 2 ? c2 : c3;
  int* off = b == 0 ? o0 : b == 1 ? o1 : b == 2 ? o2 : o3;
  int* cur = b == 0 ? u0 : b == 1 ? u1 : b == 2 ? u2 : u3;
  const int n = b == 0 ? N0 : b == 1 ? N1 : b == 2 ? N2 : N3;

  __shared__ int part[256];
  const int chunk = (n + 255) / 256;
  const int start = threadIdx.x * chunk;
  const int end = min(start + chunk, n);
  int s = 0;
  for (int i = start; i < end; ++i) s += counts[i];
  part[threadIdx.x] = s;
  __syncthreads();
  for (int d = 1; d < 256; d <<= 1) {
    int v = (threadIdx.x >= d) ? part[threadIdx.x - d] : 0;
    __syncthreads();
    part[threadIdx.x] += v;
    __syncthreads();
  }
  int run = (threadIdx.x == 0) ? 0 : part[threadIdx.x - 1];
  for (int i = start; i < end; ++i) {
    off[i] = run;
    cur[i] = run;
    run += counts[i];
  }
  if (threadIdx.x == 255) off[n] = run;
}

__global__ __launch_bounds__(256) void csr_bucket_kernel(
    const int* __restrict__ r0, const int* __restrict__ r1,
    const int* __restrict__ r2, const int* __restrict__ r3,
    int* __restrict__ u0, int* __restrict__ u1,
    int* __restrict__ u2, int* __restrict__ u3,
    int* __restrict__ b0, int* __restrict__ b1,
    int* __restrict__ b2, int* __restrict__ b3) {
  int i = blockIdx.x * 256 + threadIdx.x;
  if (i < NNZ0) { int p = atomicAdd(&u0[r0[i]], 1); b0[p] = i; }
  else if (i < NNZ0 + NNZ1) { int e = i - NNZ0; int p = atomicAdd(&u1[r1[e]], 1); b1[p] = e; }
  else if (i < NNZ0 + NNZ1 + NNZ2) { int e = i - NNZ0 - NNZ1; int p = atomicAdd(&u2[r2[e]], 1); b2[p] = e; }
  else if (i < NNZ0 + NNZ1 + NNZ2 + NNZ3) { int e = i - NNZ0 - NNZ1 - NNZ2; int p = atomicAdd(&u3[r3[e]], 1); b3[p] = e; }
}

// ---------------------------------------------------------------------------
// CSR gather pool: out[t,row,c] = sum_{j in row bucket} vals[e]*x[t,cols[e],c]
// thread = ((t*n_out+row)*C + c), c fastest -> bucket/cols/vals wave-uniform,
// x reads & out writes coalesced. bf16 in, bf16 out (fp32 accum).
// ---------------------------------------------------------------------------
template <int C>
__global__ __launch_bounds__(256) void pool_csr_kernel(
    const __bf16* __restrict__ x, const int* __restrict__ off,
    const int* __restrict__ bkt, const int* __restrict__ cols,
    const float* __restrict__ vals, __bf16* __restrict__ out,
    int n_in, int n_out) {
  unsigned id = blockIdx.x * 256u + threadIdx.x;
  unsigned total = (unsigned)n_out * T_FRAMES * C;
  if (id >= total) return;
  int c = id % C;
  unsigned rt = id / C;
  int row = rt % n_out;
  int t = rt / n_out;
  int o0 = off[row], o1 = off[row + 1];
  float acc = 0.f;
  for (int j = o0; j < o1; ++j) {
    int e = bkt[j];
    acc = fmaf(vals[e], (float)x[(t * n_in + cols[e]) * C + c], acc);
  }
  out[id] = (__bf16)acc;
}

// ---------------------------------------------------------------------------
// spiral conv as bf16 MFMA GEMM.  A[m,k] = x[t, idx[v, k/CIN], k%CIN], m=t*n+v
// W (bf16) is [COUT][K] row-major = B^T; D = A.B via mfma_f32_16x16x32_bf16.
// One wave per 16-row M-tile; M = 64n ≡ 0 mod 16, grid = n blocks of 4 waves.
// s/ci0 are unroll-constants (rule #20: keeps base[] statically indexed).
// ---------------------------------------------------------------------------
template <int CIN, int COUT>
__global__ __launch_bounds__(256) void conv_mfma_kernel(
    const __bf16* __restrict__ x, const int* __restrict__ idx,
    const __bf16* __restrict__ Wb, const float* __restrict__ bias,
    __bf16* __restrict__ out, int n) {
  constexpr int K = 9 * CIN;
  constexpr int KK = K / 32;
  constexpr int NT = COUT / 16;

  const int lane = threadIdx.x & 63;
  const int wid = threadIdx.x >> 6;
  const int mtile = blockIdx.x * 4 + wid;
  const int col = lane & 15;
  const int kg = lane >> 4;

  const int m = mtile * 16 + col;   // gather row for A-frag
  const int t = m / n;
  const int v = m - t * n;

  int base[9];
#pragma unroll
  for (int s = 0; s < 9; ++s) base[s] = (t * n + idx[v * 9 + s]) * CIN;

  f32x4 acc[NT];
#pragma unroll
  for (int nt = 0; nt < NT; ++nt) {
    float b = bias[nt * 16 + col];
    acc[nt] = (f32x4){b, b, b, b};
  }

#pragma unroll
  for (int kk = 0; kk < KK; ++kk) {
    const int s = (kk * 32) / CIN;      // constant under unroll (CIN mult of 32)
    const int ci0 = (kk * 32) % CIN;    // constant under unroll
    bf16x8 a = *(const bf16x8*)(x + base[s] + ci0 + kg * 8);
#pragma unroll
    for (int nt = 0; nt < NT; ++nt) {
      bf16x8 bfr = *(const bf16x8*)(Wb + (size_t)(nt * 16 + col) * K + kk * 32 + kg * 8);
      acc[nt] = __builtin_amdgcn_mfma_f32_16x16x32_bf16(a, bfr, acc[nt], 0, 0, 0);
    }
  }

  // D: col = lane&15 (=cout within tile), row = kg*4 + j  -> flat m index
#pragma unroll
  for (int j = 0; j < 4; ++j) {
    const int mr = mtile * 16 + kg * 4 + j;
#pragma unroll
    for (int nt = 0; nt < NT; ++nt) {
      float aa = acc[nt][j];
      aa = aa > 0.f ? aa : expm1f(aa);   // ELU
      out[(size_t)mr * COUT + nt * 16 + col] = (__bf16)aa;
    }
  }
}

// ---------------------------------------------------------------------------
// final conv 32->3 (+actor) as MFMA with N padded to 16. x bf16, out fp32.
// ---------------------------------------------------------------------------
__global__ __launch_bounds__(256) void final_mfma_kernel(
    const __bf16* __restrict__ x, const int* __restrict__ idx,
    const __bf16* __restrict__ Wfp, const float* __restrict__ bf3,
    const float* __restrict__ actor, float* __restrict__ out) {
  constexpr int n = N0;
  const int lane = threadIdx.x & 63;
  const int wid = threadIdx.x >> 6;
  const int mtile = blockIdx.x * 4 + wid;
  const int col = lane & 15;
  const int kg = lane >> 4;

  const int m = mtile * 16 + col;
  const int t = m / n;
  const int v = m - t * n;

  int base[9];
#pragma unroll
  for (int s = 0; s < 9; ++s) base[s] = (t * n + idx[v * 9 + s]) * 32;

  float b = (col < 3) ? bf3[col] : 0.f;
  f32x4 acc = (f32x4){b, b, b, b};

#pragma unroll
  for (int kk = 0; kk < 9; ++kk) {
    bf16x8 a = *(const bf16x8*)(x + base[kk] + kg * 8);
    bf16x8 w = *(const bf16x8*)(Wfp + col * 288 + kk * 32 + kg * 8);
    acc = __builtin_amdgcn_mfma_f32_16x16x32_bf16(a, w, acc, 0, 0, 0);
  }

  if (col < 3) {
#pragma unroll
    for (int j = 0; j < 4; ++j) {
      const int mr = mtile * 16 + kg * 4 + j;
      const int vr = mr % n;
      out[(size_t)mr * 3 + col] = acc[j] + actor[vr * 3 + col];
    }
  }
}

// ---------------------------------------------------------------------------
extern "C" void kernel_launch(void* const* d_in, const int* in_sizes, int n_in_args,
                              void* d_out, int out_size, void* d_ws, size_t ws_size,
                              hipStream_t stream) {
  const float* latent = (const float*)d_in[0];
  const float* actor  = (const float*)d_in[1];
  const int* spiral0 = (const int*)d_in[2];
  const int* spiral1 = (const int*)d_in[3];
  const int* spiral2 = (const int*)d_in[4];
  const int* spiral3 = (const int*)d_in[5];
  const int* up0_rows = (const int*)d_in[6];
  const int* up0_cols = (const int*)d_in[7];
  const float* up0_vals = (const float*)d_in[8];
  const int* up1_rows = (const int*)d_in[9];
  const int* up1_cols = (const int*)d_in[10];
  const float* up1_vals = (const float*)d_in[11];
  const int* up2_rows = (const int*)d_in[12];
  const int* up2_cols = (const int*)d_in[13];
  const float* up2_vals = (const float*)d_in[14];
  const int* up3_rows = (const int*)d_in[15];
  const int* up3_cols = (const int*)d_in[16];
  const float* up3_vals = (const float*)d_in[17];
  const float* W0 = (const float*)d_in[18];
  const float* b0 = (const float*)d_in[19];
  const float* W1 = (const float*)d_in[20];
  const float* b1 = (const float*)d_in[21];
  const float* W2 = (const float*)d_in[22];
  const float* b2 = (const float*)d_in[23];
  const float* W3 = (const float*)d_in[24];
  const float* b3 = (const float*)d_in[25];
  const float* W4 = (const float*)d_in[26];
  const float* b4 = (const float*)d_in[27];
  const float* Wf = (const float*)d_in[28];
  const float* bf3 = (const float*)d_in[29];
  float* out = (float*)d_out;

  // ---- workspace layout (~62.4 MB) ----
  __bf16* poolbuf = (__bf16*)d_ws;              // 20,574,208 bf16 (41.1 MB)
  __bf16* convout = poolbuf + 20574208;         // 10,287,104 bf16 (20.6 MB)
  __bf16* wbuf = convout + 10287104;            // 281,088 bf16 (0.56 MB)
  __bf16* W1b = wbuf;                           // 128*1152
  __bf16* W2b = W1b + 147456;                   // 64*1152
  __bf16* W3b = W2b + 73728;                    // 64*576
  __bf16* W4b = W3b + 36864;                    // 32*576
  __bf16* Wfp = W4b + 18432;                    // 16*288 zero-padded
  int* csr = (int*)(wbuf + 281088);             // byte offset 62,284,800 (4B aligned)
  int* cnt0 = csr;            int* cnt1 = cnt0 + N0;   int* cnt2 = cnt1 + N1;   int* cnt3 = cnt2 + N2;
  int* off0 = csr + 6672;     int* off1 = off0 + N0+1; int* off2 = off1 + N1+1; int* off3 = off2 + N2+1;
  int* cur0 = csr + 13348;    int* cur1 = cur0 + N0;   int* cur2 = cur1 + N1;   int* cur3 = cur2 + N2;
  int* bkt0 = csr + 20020;    int* bkt1 = bkt0 + NNZ0; int* bkt2 = bkt1 + NNZ1; int* bkt3 = bkt2 + NNZ2;

  // ---- CSR build (counts zeroed; cursor/offsets fully written by scan) ----
  hipMemsetAsync(cnt0, 0, 6672 * sizeof(int), stream);
  csr_count_kernel<<<(20016 + 255) / 256, 256, 0, stream>>>(
      up0_rows, up1_rows, up2_rows, up3_rows, cnt0, cnt1, cnt2, cnt3);
  csr_scan_kernel<<<4, 256, 0, stream>>>(cnt0, cnt1, cnt2, cnt3,
                                         off0, off1, off2, off3,
                                         cur0, cur1, cur2, cur3);
  csr_bucket_kernel<<<(20016 + 255) / 256, 256, 0, stream>>>(
      up0_rows, up1_rows, up2_rows, up3_rows,
      cur0, cur1, cur2, cur3, bkt0, bkt1, bkt2, bkt3);

  // ---- weights -> bf16 ----
  cvt_all_kernel<<<(281088 + 255) / 256, 256, 0, stream>>>(W1, W2, W3, W4, Wf, wbuf);

  // ---- dense: latent -> [64,20,128] bf16 ----
  linear0_kernel<<<(64 * 2560 + 255) / 256, 256, 0, stream>>>(latent, W0, b0, convout);

  // ---- level 3: pool 20->79 (C=128), conv 128->128 ----
  pool_csr_kernel<128><<<(64 * N3 * 128 + 255) / 256, 256, 0, stream>>>(
      convout, off3, bkt3, up3_cols, up3_vals, poolbuf, N4, N3);
  conv_mfma_kernel<128, 128><<<N3, 256, 0, stream>>>(poolbuf, spiral3, W1b, b1, convout, N3);

  // ---- level 2: pool 79->314 (C=128), conv 128->64 ----
  pool_csr_kernel<128><<<(64 * N2 * 128 + 255) / 256, 256, 0, stream>>>(
      convout, off2, bkt2, up2_cols, up2_vals, poolbuf, N3, N2);
  conv_mfma_kernel<128, 64><<<N2, 256, 0, stream>>>(poolbuf, spiral2, W2b, b2, convout, N2);

  // ---- level 1: pool 314->1256 (C=64), conv 64->64 ----
  pool_csr_kernel<64><<<(64 * N1 * 64 + 255) / 256, 256, 0, stream>>>(
      convout, off1, bkt1, up1_cols, up1_vals, poolbuf, N2, N1);
  conv_mfma_kernel<64, 64><<<N1, 256, 0, stream>>>(poolbuf, spiral1, W3b, b3, convout, N1);

  // ---- level 0: pool 1256->5023 (C=64), conv 64->32 ----
  {
    unsigned tot = 64u * N0 * 64;
    pool_csr_kernel<64><<<(tot + 255) / 256, 256, 0, stream>>>(
        convout, off0, bkt0, up0_cols, up0_vals, poolbuf, N1, N0);
  }
  conv_mfma_kernel<64, 32><<<N0, 256, 0, stream>>>(poolbuf, spiral0, W4b, b4, convout, N0);

  // ---- final conv 32->3 + actor (MFMA, N padded to 16) ----
  final_mfma_kernel<<<N0, 256, 0, stream>>>(convout, spiral0, Wfp, bf3, actor, out);
}

// Round 5
// 480.598 us; speedup vs baseline: 5.8236x; 1.3214x over previous
//
#include <hip/hip_runtime.h>
#include <hip/hip_bf16.h>

#define T_FRAMES 64

typedef __bf16 bf16x8 __attribute__((ext_vector_type(8)));
typedef float f32x4 __attribute__((ext_vector_type(4)));

// edge counts per level (fine->coarse): nnz = 3 * n_fine
#define NNZ0 15069
#define NNZ1 3768
#define NNZ2 942
#define NNZ3 237
#define N0 5023
#define N1 1256
#define N2 314
#define N3 79
#define N4 20

// ---------------------------------------------------------------------------
// de_layers[0]: x0[t, j] = latent[t,:] . W0[j,:] + b0[j]  -> bf16 out
// ---------------------------------------------------------------------------
__global__ __launch_bounds__(256) void linear0_kernel(
    const float* __restrict__ latent, const float* __restrict__ W0,
    const float* __restrict__ b0, __bf16* __restrict__ out) {
  int id = blockIdx.x * 256 + threadIdx.x;
  if (id >= 64 * 2560) return;
  int j = id % 2560;
  int t = id / 2560;
  const float* lrow = latent + t * 128;
  const float* wrow = W0 + j * 128;
  float acc = b0[j];
#pragma unroll 8
  for (int k = 0; k < 128; ++k) acc = fmaf(lrow[k], wrow[k], acc);
  out[id] = (__bf16)acc;
}

// ---------------------------------------------------------------------------
// all weights fp32 -> bf16 in one kernel (wbuf contiguous; Wf zero-padded
// from 3x288 to 16x288)
// ---------------------------------------------------------------------------
__global__ __launch_bounds__(256) void cvt_all_kernel(
    const float* __restrict__ W1, const float* __restrict__ W2,
    const float* __restrict__ W3, const float* __restrict__ W4,
    const float* __restrict__ Wf, __bf16* __restrict__ o) {
  int i = blockIdx.x * 256 + threadIdx.x;
  if (i < 147456) { o[i] = (__bf16)W1[i]; return; }
  if (i < 221184) { o[i] = (__bf16)W2[i - 147456]; return; }
  if (i < 258048) { o[i] = (__bf16)W3[i - 221184]; return; }
  if (i < 276480) { o[i] = (__bf16)W4[i - 258048]; return; }
  if (i < 281088) {
    int j = i - 276480;
    o[i] = (j / 288 < 3) ? (__bf16)Wf[j] : (__bf16)0.f;
  }
}

// ---------------------------------------------------------------------------
// CSR build: count -> scan (per-level block) -> packed bucket fill
// packed record: int2 {col, float_bits(val)} -> one 8B load, one less hop
// ---------------------------------------------------------------------------
__global__ __launch_bounds__(256) void csr_count_kernel(
    const int* __restrict__ r0, const int* __restrict__ r1,
    const int* __restrict__ r2, const int* __restrict__ r3,
    int* __restrict__ c0, int* __restrict__ c1,
    int* __restrict__ c2, int* __restrict__ c3) {
  int i = blockIdx.x * 256 + threadIdx.x;
  if (i < NNZ0) atomicAdd(&c0[r0[i]], 1);
  else if (i < NNZ0 + NNZ1) atomicAdd(&c1[r1[i - NNZ0]], 1);
  else if (i < NNZ0 + NNZ1 + NNZ2) atomicAdd(&c2[r2[i - NNZ0 - NNZ1]], 1);
  else if (i < NNZ0 + NNZ1 + NNZ2 + NNZ3) atomicAdd(&c3[r3[i - NNZ0 - NNZ1 - NNZ2]], 1);
}

__global__ __launch_bounds__(256) void csr_scan_kernel(
    const int* __restrict__ c0, const int* __restrict__ c1,
    const int* __restrict__ c2, const int* __restrict__ c3,
    int* __restrict__ o0, int* __restrict__ o1,
    int* __restrict__ o2, int* __restrict__ o3,
    int* __restrict__ u0, int* __restrict__ u1,
    int* __restrict__ u2, int* __restrict__ u3) {
  const int b = blockIdx.x;
  const int* counts = b == 0 ? c0 : b == 1 ? c1 : b == 2 ? c2 : c3;
  int* off = b == 0 ? o0 : b == 1 ? o1 : b == 2 ? o2 : o3;
  int* cur = b == 0 ? u0 : b == 1 ? u1 : b == 2 ? u2 : u3;
  const int n = b == 0 ? N0 : b == 1 ? N1 : b == 2 ? N2 : N3;

  __shared__ int part[256];
  const int chunk = (n + 255) / 256;
  const int start = threadIdx.x * chunk;
  const int end = min(start + chunk, n);
  int s = 0;
  for (int i = start; i < end; ++i) s += counts[i];
  part[threadIdx.x] = s;
  __syncthreads();
  for (int d = 1; d < 256; d <<= 1) {
    int v = (threadIdx.x >= d) ? part[threadIdx.x - d] : 0;
    __syncthreads();
    part[threadIdx.x] += v;
    __syncthreads();
  }
  int run = (threadIdx.x == 0) ? 0 : part[threadIdx.x - 1];
  for (int i = start; i < end; ++i) {
    off[i] = run;
    cur[i] = run;
    run += counts[i];
  }
  if (threadIdx.x == 255) off[n] = run;
}

__global__ __launch_bounds__(256) void csr_bucket_kernel(
    const int* __restrict__ r0, const int* __restrict__ r1,
    const int* __restrict__ r2, const int* __restrict__ r3,
    const int* __restrict__ q0, const int* __restrict__ q1,
    const int* __restrict__ q2, const int* __restrict__ q3,
    const float* __restrict__ v0, const float* __restrict__ v1,
    const float* __restrict__ v2, const float* __restrict__ v3,
    int* __restrict__ u0, int* __restrict__ u1,
    int* __restrict__ u2, int* __restrict__ u3,
    int2* __restrict__ p0, int2* __restrict__ p1,
    int2* __restrict__ p2, int2* __restrict__ p3) {
  int i = blockIdx.x * 256 + threadIdx.x;
  if (i < NNZ0) {
    int p = atomicAdd(&u0[r0[i]], 1);
    p0[p] = make_int2(q0[i], __float_as_int(v0[i]));
  } else if (i < NNZ0 + NNZ1) {
    int e = i - NNZ0;
    int p = atomicAdd(&u1[r1[e]], 1);
    p1[p] = make_int2(q1[e], __float_as_int(v1[e]));
  } else if (i < NNZ0 + NNZ1 + NNZ2) {
    int e = i - NNZ0 - NNZ1;
    int p = atomicAdd(&u2[r2[e]], 1);
    p2[p] = make_int2(q2[e], __float_as_int(v2[e]));
  } else if (i < NNZ0 + NNZ1 + NNZ2 + NNZ3) {
    int e = i - NNZ0 - NNZ1 - NNZ2;
    int p = atomicAdd(&u3[r3[e]], 1);
    p3[p] = make_int2(q3[e], __float_as_int(v3[e]));
  }
}

// ---------------------------------------------------------------------------
// CSR gather pool, t-tiled: thread = (t-block of TT, row, c); edge metadata
// loaded once per row (wave-uniform), then TT independent x loads per edge
// (ILP hides latency). bf16 in/out, fp32 accum.
// ---------------------------------------------------------------------------
template <int C, int TT>
__global__ __launch_bounds__(256) void pool_csr_kernel(
    const __bf16* __restrict__ x, const int* __restrict__ off,
    const int2* __restrict__ pk, __bf16* __restrict__ out,
    int n_in, int n_out) {
  unsigned id = blockIdx.x * 256u + threadIdx.x;
  unsigned total = (unsigned)n_out * (T_FRAMES / TT) * C;
  if (id >= total) return;
  const int c = id % C;
  const unsigned rt = id / C;
  const int row = rt % n_out;
  const int tb = rt / n_out;

  const int o0 = off[row], o1 = off[row + 1];
  float acc[TT];
#pragma unroll
  for (int u = 0; u < TT; ++u) acc[u] = 0.f;

  for (int j = o0; j < o1; ++j) {
    const int2 rec = pk[j];
    const float val = __int_as_float(rec.y);
    const __bf16* xp = x + ((size_t)(tb * TT) * n_in + rec.x) * C + c;
#pragma unroll
    for (int u = 0; u < TT; ++u)
      acc[u] = fmaf(val, (float)xp[(size_t)u * n_in * C], acc[u]);
  }

#pragma unroll
  for (int u = 0; u < TT; ++u)
    out[((size_t)(tb * TT + u) * n_out + row) * C + c] = (__bf16)acc[u];
}

// ---------------------------------------------------------------------------
// spiral conv as bf16 MFMA GEMM.  A[m,k] = x[t, idx[v, k/CIN], k%CIN], m=t*n+v
// W (bf16) is [COUT][K] row-major = B^T; D = A.B via mfma_f32_16x16x32_bf16.
// One wave per 16-row M-tile; M = 64n ≡ 0 mod 16, grid = n blocks of 4 waves.
// ---------------------------------------------------------------------------
template <int CIN, int COUT>
__global__ __launch_bounds__(256) void conv_mfma_kernel(
    const __bf16* __restrict__ x, const int* __restrict__ idx,
    const __bf16* __restrict__ Wb, const float* __restrict__ bias,
    __bf16* __restrict__ out, int n) {
  constexpr int K = 9 * CIN;
  constexpr int KK = K / 32;
  constexpr int NT = COUT / 16;

  const int lane = threadIdx.x & 63;
  const int wid = threadIdx.x >> 6;
  const int mtile = blockIdx.x * 4 + wid;
  const int col = lane & 15;
  const int kg = lane >> 4;

  const int m = mtile * 16 + col;   // gather row for A-frag
  const int t = m / n;
  const int v = m - t * n;

  int base[9];
#pragma unroll
  for (int s = 0; s < 9; ++s) base[s] = (t * n + idx[v * 9 + s]) * CIN;

  f32x4 acc[NT];
#pragma unroll
  for (int nt = 0; nt < NT; ++nt) {
    float b = bias[nt * 16 + col];
    acc[nt] = (f32x4){b, b, b, b};
  }

#pragma unroll
  for (int kk = 0; kk < KK; ++kk) {
    const int s = (kk * 32) / CIN;      // constant under unroll
    const int ci0 = (kk * 32) % CIN;    // constant under unroll
    bf16x8 a = *(const bf16x8*)(x + base[s] + ci0 + kg * 8);
#pragma unroll
    for (int nt = 0; nt < NT; ++nt) {
      bf16x8 bfr = *(const bf16x8*)(Wb + (size_t)(nt * 16 + col) * K + kk * 32 + kg * 8);
      acc[nt] = __builtin_amdgcn_mfma_f32_16x16x32_bf16(a, bfr, acc[nt], 0, 0, 0);
    }
  }

  // D: col = lane&15 (=cout within tile), row = kg*4 + j  -> flat m index
#pragma unroll
  for (int j = 0; j < 4; ++j) {
    const int mr = mtile * 16 + kg * 4 + j;
#pragma unroll
    for (int nt = 0; nt < NT; ++nt) {
      float aa = acc[nt][j];
      aa = aa > 0.f ? aa : expm1f(aa);   // ELU
      out[(size_t)mr * COUT + nt * 16 + col] = (__bf16)aa;
    }
  }
}

// ---------------------------------------------------------------------------
// final conv 32->3 (+actor) as MFMA with N padded to 16. x bf16, out fp32.
// ---------------------------------------------------------------------------
__global__ __launch_bounds__(256) void final_mfma_kernel(
    const __bf16* __restrict__ x, const int* __restrict__ idx,
    const __bf16* __restrict__ Wfp, const float* __restrict__ bf3,
    const float* __restrict__ actor, float* __restrict__ out) {
  constexpr int n = N0;
  const int lane = threadIdx.x & 63;
  const int wid = threadIdx.x >> 6;
  const int mtile = blockIdx.x * 4 + wid;
  const int col = lane & 15;
  const int kg = lane >> 4;

  const int m = mtile * 16 + col;
  const int t = m / n;
  const int v = m - t * n;

  int base[9];
#pragma unroll
  for (int s = 0; s < 9; ++s) base[s] = (t * n + idx[v * 9 + s]) * 32;

  float b = (col < 3) ? bf3[col] : 0.f;
  f32x4 acc = (f32x4){b, b, b, b};

#pragma unroll
  for (int kk = 0; kk < 9; ++kk) {
    bf16x8 a = *(const bf16x8*)(x + base[kk] + kg * 8);
    bf16x8 w = *(const bf16x8*)(Wfp + col * 288 + kk * 32 + kg * 8);
    acc = __builtin_amdgcn_mfma_f32_16x16x32_bf16(a, w, acc, 0, 0, 0);
  }

  if (col < 3) {
#pragma unroll
    for (int j = 0; j < 4; ++j) {
      const int mr = mtile * 16 + kg * 4 + j;
      const int vr = mr % n;
      out[(size_t)mr * 3 + col] = acc[j] + actor[vr * 3 + col];
    }
  }
}

// ---------------------------------------------------------------------------
extern "C" void kernel_launch(void* const* d_in, const int* in_sizes, int n_in_args,
                              void* d_out, int out_size, void* d_ws, size_t ws_size,
                              hipStream_t stream) {
  const float* latent = (const float*)d_in[0];
  const float* actor  = (const float*)d_in[1];
  const int* spiral0 = (const int*)d_in[2];
  const int* spiral1 = (const int*)d_in[3];
  const int* spiral2 = (const int*)d_in[4];
  const int* spiral3 = (const int*)d_in[5];
  const int* up0_rows = (const int*)d_in[6];
  const int* up0_cols = (const int*)d_in[7];
  const float* up0_vals = (const float*)d_in[8];
  const int* up1_rows = (const int*)d_in[9];
  const int* up1_cols = (const int*)d_in[10];
  const float* up1_vals = (const float*)d_in[11];
  const int* up2_rows = (const int*)d_in[12];
  const int* up2_cols = (const int*)d_in[13];
  const float* up2_vals = (const float*)d_in[14];
  const int* up3_rows = (const int*)d_in[15];
  const int* up3_cols = (const int*)d_in[16];
  const float* up3_vals = (const float*)d_in[17];
  const float* W0 = (const float*)d_in[18];
  const float* b0 = (const float*)d_in[19];
  const float* W1 = (const float*)d_in[20];
  const float* b1 = (const float*)d_in[21];
  const float* W2 = (const float*)d_in[22];
  const float* b2 = (const float*)d_in[23];
  const float* W3 = (const float*)d_in[24];
  const float* b3 = (const float*)d_in[25];
  const float* W4 = (const float*)d_in[26];
  const float* b4 = (const float*)d_in[27];
  const float* Wf = (const float*)d_in[28];
  const float* bf3 = (const float*)d_in[29];
  float* out = (float*)d_out;

  // ---- workspace layout (~62.5 MB) ----
  __bf16* poolbuf = (__bf16*)d_ws;              // 20,574,208 bf16 (41.1 MB)
  __bf16* convout = poolbuf + 20574208;         // 10,287,104 bf16 (20.6 MB)
  __bf16* wbuf = convout + 10287104;            // 281,088 bf16 (0.56 MB)
  __bf16* W1b = wbuf;                           // 128*1152
  __bf16* W2b = W1b + 147456;                   // 64*1152
  __bf16* W3b = W2b + 73728;                    // 64*576
  __bf16* W4b = W3b + 36864;                    // 32*576
  __bf16* Wfp = W4b + 18432;                    // 16*288 zero-padded
  int* csr = (int*)(wbuf + 281088);             // byte offset 62,284,800
  int* cnt0 = csr;            int* cnt1 = cnt0 + N0;   int* cnt2 = cnt1 + N1;   int* cnt3 = cnt2 + N2;
  int* off0 = csr + 6672;     int* off1 = off0 + N0+1; int* off2 = off1 + N1+1; int* off3 = off2 + N2+1;
  int* cur0 = csr + 13348;    int* cur1 = cur0 + N0;   int* cur2 = cur1 + N1;   int* cur3 = cur2 + N2;
  int2* pk0 = (int2*)(csr + 20020);             // byte offset 62,364,880 (8B aligned)
  int2* pk1 = pk0 + NNZ0;
  int2* pk2 = pk1 + NNZ1;
  int2* pk3 = pk2 + NNZ2;

  // ---- CSR build ----
  hipMemsetAsync(cnt0, 0, 6672 * sizeof(int), stream);
  csr_count_kernel<<<(20016 + 255) / 256, 256, 0, stream>>>(
      up0_rows, up1_rows, up2_rows, up3_rows, cnt0, cnt1, cnt2, cnt3);
  csr_scan_kernel<<<4, 256, 0, stream>>>(cnt0, cnt1, cnt2, cnt3,
                                         off0, off1, off2, off3,
                                         cur0, cur1, cur2, cur3);
  csr_bucket_kernel<<<(20016 + 255) / 256, 256, 0, stream>>>(
      up0_rows, up1_rows, up2_rows, up3_rows,
      up0_cols, up1_cols, up2_cols, up3_cols,
      up0_vals, up1_vals, up2_vals, up3_vals,
      cur0, cur1, cur2, cur3, pk0, pk1, pk2, pk3);

  // ---- weights -> bf16 ----
  cvt_all_kernel<<<(281088 + 255) / 256, 256, 0, stream>>>(W1, W2, W3, W4, Wf, wbuf);

  // ---- dense: latent -> [64,20,128] bf16 ----
  linear0_kernel<<<(64 * 2560 + 255) / 256, 256, 0, stream>>>(latent, W0, b0, convout);

  // ---- level 3: pool 20->79 (C=128, TT=16), conv 128->128 ----
  pool_csr_kernel<128, 16><<<(N3 * 4 * 128 + 255) / 256, 256, 0, stream>>>(
      convout, off3, pk3, poolbuf, N4, N3);
  conv_mfma_kernel<128, 128><<<N3, 256, 0, stream>>>(poolbuf, spiral3, W1b, b1, convout, N3);

  // ---- level 2: pool 79->314 (C=128, TT=16), conv 128->64 ----
  pool_csr_kernel<128, 16><<<(N2 * 4 * 128 + 255) / 256, 256, 0, stream>>>(
      convout, off2, pk2, poolbuf, N3, N2);
  conv_mfma_kernel<128, 64><<<N2, 256, 0, stream>>>(poolbuf, spiral2, W2b, b2, convout, N2);

  // ---- level 1: pool 314->1256 (C=64, TT=16), conv 64->64 ----
  pool_csr_kernel<64, 16><<<(N1 * 4 * 64 + 255) / 256, 256, 0, stream>>>(
      convout, off1, pk1, poolbuf, N2, N1);
  conv_mfma_kernel<64, 64><<<N1, 256, 0, stream>>>(poolbuf, spiral1, W3b, b3, convout, N1);

  // ---- level 0: pool 1256->5023 (C=64, TT=16), conv 64->32 ----
  pool_csr_kernel<64, 16><<<(N0 * 4 * 64 + 255) / 256, 256, 0, stream>>>(
      convout, off0, pk0, poolbuf, N1, N0);
  conv_mfma_kernel<64, 32><<<N0, 256, 0, stream>>>(poolbuf, spiral0, W4b, b4, convout, N0);

  // ---- final conv 32->3 + actor (MFMA, N padded to 16) ----
  final_mfma_kernel<<<N0, 256, 0, stream>>>(convout, spiral0, Wfp, bf3, actor, out);
}

// Round 6
// 458.322 us; speedup vs baseline: 6.1066x; 1.0486x over previous
//
#include <hip/hip_runtime.h>
#include <hip/hip_bf16.h>

#define T_FRAMES 64

typedef __bf16 bf16x8 __attribute__((ext_vector_type(8)));
typedef float f32x4 __attribute__((ext_vector_type(4)));

// edge counts per level (fine->coarse): nnz = 3 * n_fine
#define NNZ0 15069
#define NNZ1 3768
#define NNZ2 942
#define NNZ3 237
#define N0 5023
#define N1 1256
#define N2 314
#define N3 79
#define N4 20

// All activation buffers are vt-major: [vert][t][C] (t-rows of one vertex
// contiguous -> spiral gathers read dense 8KB slabs instead of random 64B).
// Final output d_out stays [t][v][3] per reference.

// ---------------------------------------------------------------------------
// de_layers[0]: x0[t, vert, ci] = latent[t,:].W0[vert*128+ci,:] + b0
// stored vt-major: out[(vert*64+t)*128+ci]
// ---------------------------------------------------------------------------
__global__ __launch_bounds__(256) void linear0_kernel(
    const float* __restrict__ latent, const float* __restrict__ W0,
    const float* __restrict__ b0, __bf16* __restrict__ out) {
  int id = blockIdx.x * 256 + threadIdx.x;
  if (id >= 64 * 2560) return;
  int j = id % 2560;
  int t = id / 2560;
  const float* lrow = latent + t * 128;
  const float* wrow = W0 + j * 128;
  float acc = b0[j];
#pragma unroll 8
  for (int k = 0; k < 128; ++k) acc = fmaf(lrow[k], wrow[k], acc);
  out[((size_t)(j >> 7) * 64 + t) * 128 + (j & 127)] = (__bf16)acc;
}

// ---------------------------------------------------------------------------
// all weights fp32 -> bf16 (wbuf contiguous; Wf zero-padded 3x288 -> 16x288)
// ---------------------------------------------------------------------------
__global__ __launch_bounds__(256) void cvt_all_kernel(
    const float* __restrict__ W1, const float* __restrict__ W2,
    const float* __restrict__ W3, const float* __restrict__ W4,
    const float* __restrict__ Wf, __bf16* __restrict__ o) {
  int i = blockIdx.x * 256 + threadIdx.x;
  if (i < 147456) { o[i] = (__bf16)W1[i]; return; }
  if (i < 221184) { o[i] = (__bf16)W2[i - 147456]; return; }
  if (i < 258048) { o[i] = (__bf16)W3[i - 221184]; return; }
  if (i < 276480) { o[i] = (__bf16)W4[i - 258048]; return; }
  if (i < 281088) {
    int j = i - 276480;
    o[i] = (j / 288 < 3) ? (__bf16)Wf[j] : (__bf16)0.f;
  }
}

// ---------------------------------------------------------------------------
// CSR build: count -> scan (per-level block) -> packed bucket fill
// packed record: int2 {col, float_bits(val)}
// ---------------------------------------------------------------------------
__global__ __launch_bounds__(256) void csr_count_kernel(
    const int* __restrict__ r0, const int* __restrict__ r1,
    const int* __restrict__ r2, const int* __restrict__ r3,
    int* __restrict__ c0, int* __restrict__ c1,
    int* __restrict__ c2, int* __restrict__ c3) {
  int i = blockIdx.x * 256 + threadIdx.x;
  if (i < NNZ0) atomicAdd(&c0[r0[i]], 1);
  else if (i < NNZ0 + NNZ1) atomicAdd(&c1[r1[i - NNZ0]], 1);
  else if (i < NNZ0 + NNZ1 + NNZ2) atomicAdd(&c2[r2[i - NNZ0 - NNZ1]], 1);
  else if (i < NNZ0 + NNZ1 + NNZ2 + NNZ3) atomicAdd(&c3[r3[i - NNZ0 - NNZ1 - NNZ2]], 1);
}

__global__ __launch_bounds__(256) void csr_scan_kernel(
    const int* __restrict__ c0, const int* __restrict__ c1,
    const int* __restrict__ c2, const int* __restrict__ c3,
    int* __restrict__ o0, int* __restrict__ o1,
    int* __restrict__ o2, int* __restrict__ o3,
    int* __restrict__ u0, int* __restrict__ u1,
    int* __restrict__ u2, int* __restrict__ u3) {
  const int b = blockIdx.x;
  const int* counts = b == 0 ? c0 : b == 1 ? c1 : b == 2 ? c2 : c3;
  int* off = b == 0 ? o0 : b == 1 ? o1 : b == 2 ? o2 : o3;
  int* cur = b == 0 ? u0 : b == 1 ? u1 : b == 2 ? u2 : u3;
  const int n = b == 0 ? N0 : b == 1 ? N1 : b == 2 ? N2 : N3;

  __shared__ int part[256];
  const int chunk = (n + 255) / 256;
  const int start = threadIdx.x * chunk;
  const int end = min(start + chunk, n);
  int s = 0;
  for (int i = start; i < end; ++i) s += counts[i];
  part[threadIdx.x] = s;
  __syncthreads();
  for (int d = 1; d < 256; d <<= 1) {
    int v = (threadIdx.x >= d) ? part[threadIdx.x - d] : 0;
    __syncthreads();
    part[threadIdx.x] += v;
    __syncthreads();
  }
  int run = (threadIdx.x == 0) ? 0 : part[threadIdx.x - 1];
  for (int i = start; i < end; ++i) {
    off[i] = run;
    cur[i] = run;
    run += counts[i];
  }
  if (threadIdx.x == 255) off[n] = run;
}

__global__ __launch_bounds__(256) void csr_bucket_kernel(
    const int* __restrict__ r0, const int* __restrict__ r1,
    const int* __restrict__ r2, const int* __restrict__ r3,
    const int* __restrict__ q0, const int* __restrict__ q1,
    const int* __restrict__ q2, const int* __restrict__ q3,
    const float* __restrict__ v0, const float* __restrict__ v1,
    const float* __restrict__ v2, const float* __restrict__ v3,
    int* __restrict__ u0, int* __restrict__ u1,
    int* __restrict__ u2, int* __restrict__ u3,
    int2* __restrict__ p0, int2* __restrict__ p1,
    int2* __restrict__ p2, int2* __restrict__ p3) {
  int i = blockIdx.x * 256 + threadIdx.x;
  if (i < NNZ0) {
    int p = atomicAdd(&u0[r0[i]], 1);
    p0[p] = make_int2(q0[i], __float_as_int(v0[i]));
  } else if (i < NNZ0 + NNZ1) {
    int e = i - NNZ0;
    int p = atomicAdd(&u1[r1[e]], 1);
    p1[p] = make_int2(q1[e], __float_as_int(v1[e]));
  } else if (i < NNZ0 + NNZ1 + NNZ2) {
    int e = i - NNZ0 - NNZ1;
    int p = atomicAdd(&u2[r2[e]], 1);
    p2[p] = make_int2(q2[e], __float_as_int(v2[e]));
  } else if (i < NNZ0 + NNZ1 + NNZ2 + NNZ3) {
    int e = i - NNZ0 - NNZ1 - NNZ2;
    int p = atomicAdd(&u3[r3[e]], 1);
    p3[p] = make_int2(q3[e], __float_as_int(v3[e]));
  }
}

// ---------------------------------------------------------------------------
// CSR gather pool, vt-major: out[row][t][c] = sum val * x[col][t][c].
// thread = (row, t-block of TT, c); edge meta wave-uniform; x reads for the
// TT frames are TT consecutive C-rows (dense 2KB per wave per edge).
// ---------------------------------------------------------------------------
template <int C, int TT>
__global__ __launch_bounds__(256) void pool_csr_kernel(
    const __bf16* __restrict__ x, const int* __restrict__ off,
    const int2* __restrict__ pk, __bf16* __restrict__ out, int n_out) {
  unsigned id = blockIdx.x * 256u + threadIdx.x;
  unsigned total = (unsigned)n_out * (T_FRAMES / TT) * C;
  if (id >= total) return;
  const int c = id % C;
  const unsigned rt = id / C;
  const int tb = rt % (T_FRAMES / TT);
  const int row = rt / (T_FRAMES / TT);

  const int o0 = off[row], o1 = off[row + 1];
  float acc[TT];
#pragma unroll
  for (int u = 0; u < TT; ++u) acc[u] = 0.f;

  for (int j = o0; j < o1; ++j) {
    const int2 rec = pk[j];
    const float val = __int_as_float(rec.y);
    const __bf16* xp = x + ((size_t)rec.x * T_FRAMES + tb * TT) * C + c;
#pragma unroll
    for (int u = 0; u < TT; ++u)
      acc[u] = fmaf(val, (float)xp[(size_t)u * C], acc[u]);
  }

  __bf16* op = out + ((size_t)row * T_FRAMES + tb * TT) * C + c;
#pragma unroll
  for (int u = 0; u < TT; ++u) op[(size_t)u * C] = (__bf16)acc[u];
}

// ---------------------------------------------------------------------------
// spiral conv as bf16 MFMA GEMM, vt-major.
// Block (v = blockIdx.x); WV waves, wave w handles t-tile (blockIdx.y*WV+w):
// 16 t-rows of vertex v. A-row(t) = concat_s x[idx[v,s]][t][:] -> 9 dense
// slabs; idx loads are block-uniform (scalar). D row kg*4+j = t within tile.
// ---------------------------------------------------------------------------
template <int CIN, int COUT, int WV>
__global__ __launch_bounds__(256) void conv_mfma_kernel(
    const __bf16* __restrict__ x, const int* __restrict__ idx,
    const __bf16* __restrict__ Wb, const float* __restrict__ bias,
    __bf16* __restrict__ out) {
  constexpr int K = 9 * CIN;
  constexpr int KK = K / 32;
  constexpr int NT = COUT / 16;

  const int lane = threadIdx.x & 63;
  const int wid = threadIdx.x >> 6;
  const int v = blockIdx.x;
  const int tq = blockIdx.y * WV + wid;       // t-tile index 0..3
  const int col = lane & 15;
  const int kg = lane >> 4;
  const int trow = tq * 16 + col;             // A-fragment t-row

  size_t base[9];
#pragma unroll
  for (int s = 0; s < 9; ++s)
    base[s] = (size_t)idx[v * 9 + s] * (T_FRAMES * CIN) + (size_t)trow * CIN;

  f32x4 acc[NT];
#pragma unroll
  for (int nt = 0; nt < NT; ++nt) {
    float b = bias[nt * 16 + col];
    acc[nt] = (f32x4){b, b, b, b};
  }

#pragma unroll
  for (int kk = 0; kk < KK; ++kk) {
    const int s = (kk * 32) / CIN;      // constant under unroll
    const int ci0 = (kk * 32) % CIN;    // constant under unroll
    bf16x8 a = *(const bf16x8*)(x + base[s] + ci0 + kg * 8);
#pragma unroll
    for (int nt = 0; nt < NT; ++nt) {
      bf16x8 bfr = *(const bf16x8*)(Wb + (size_t)(nt * 16 + col) * K + kk * 32 + kg * 8);
      acc[nt] = __builtin_amdgcn_mfma_f32_16x16x32_bf16(a, bfr, acc[nt], 0, 0, 0);
    }
  }

  // D: col = output channel, row kg*4+j = t within tile -> store vt-major
#pragma unroll
  for (int j = 0; j < 4; ++j) {
    const size_t tr = tq * 16 + kg * 4 + j;
#pragma unroll
    for (int nt = 0; nt < NT; ++nt) {
      float aa = acc[nt][j];
      aa = aa > 0.f ? aa : expm1f(aa);   // ELU
      out[((size_t)v * T_FRAMES + tr) * COUT + nt * 16 + col] = (__bf16)aa;
    }
  }
}

// ---------------------------------------------------------------------------
// final conv 32->3 (+actor), vt-major input, [t][v][3] output (reference).
// ---------------------------------------------------------------------------
__global__ __launch_bounds__(256) void final_mfma_kernel(
    const __bf16* __restrict__ x, const int* __restrict__ idx,
    const __bf16* __restrict__ Wfp, const float* __restrict__ bf3,
    const float* __restrict__ actor, float* __restrict__ out) {
  const int lane = threadIdx.x & 63;
  const int wid = threadIdx.x >> 6;
  const int v = blockIdx.x;
  const int col = lane & 15;
  const int kg = lane >> 4;
  const int trow = wid * 16 + col;

  size_t base[9];
#pragma unroll
  for (int s = 0; s < 9; ++s)
    base[s] = (size_t)idx[v * 9 + s] * (T_FRAMES * 32) + (size_t)trow * 32;

  float b = (col < 3) ? bf3[col] : 0.f;
  f32x4 acc = (f32x4){b, b, b, b};

#pragma unroll
  for (int kk = 0; kk < 9; ++kk) {
    bf16x8 a = *(const bf16x8*)(x + base[kk] + kg * 8);
    bf16x8 w = *(const bf16x8*)(Wfp + col * 288 + kk * 32 + kg * 8);
    acc = __builtin_amdgcn_mfma_f32_16x16x32_bf16(a, w, acc, 0, 0, 0);
  }

  if (col < 3) {
    const float av = actor[v * 3 + col];
#pragma unroll
    for (int j = 0; j < 4; ++j) {
      const int tr = wid * 16 + kg * 4 + j;
      out[((size_t)tr * N0 + v) * 3 + col] = acc[j] + av;
    }
  }
}

// ---------------------------------------------------------------------------
extern "C" void kernel_launch(void* const* d_in, const int* in_sizes, int n_in_args,
                              void* d_out, int out_size, void* d_ws, size_t ws_size,
                              hipStream_t stream) {
  const float* latent = (const float*)d_in[0];
  const float* actor  = (const float*)d_in[1];
  const int* spiral0 = (const int*)d_in[2];
  const int* spiral1 = (const int*)d_in[3];
  const int* spiral2 = (const int*)d_in[4];
  const int* spiral3 = (const int*)d_in[5];
  const int* up0_rows = (const int*)d_in[6];
  const int* up0_cols = (const int*)d_in[7];
  const float* up0_vals = (const float*)d_in[8];
  const int* up1_rows = (const int*)d_in[9];
  const int* up1_cols = (const int*)d_in[10];
  const float* up1_vals = (const float*)d_in[11];
  const int* up2_rows = (const int*)d_in[12];
  const int* up2_cols = (const int*)d_in[13];
  const float* up2_vals = (const float*)d_in[14];
  const int* up3_rows = (const int*)d_in[15];
  const int* up3_cols = (const int*)d_in[16];
  const float* up3_vals = (const float*)d_in[17];
  const float* W0 = (const float*)d_in[18];
  const float* b0 = (const float*)d_in[19];
  const float* W1 = (const float*)d_in[20];
  const float* b1 = (const float*)d_in[21];
  const float* W2 = (const float*)d_in[22];
  const float* b2 = (const float*)d_in[23];
  const float* W3 = (const float*)d_in[24];
  const float* b3 = (const float*)d_in[25];
  const float* W4 = (const float*)d_in[26];
  const float* b4 = (const float*)d_in[27];
  const float* Wf = (const float*)d_in[28];
  const float* bf3 = (const float*)d_in[29];
  float* out = (float*)d_out;

  // ---- workspace layout (~62.5 MB) ----
  __bf16* poolbuf = (__bf16*)d_ws;              // 20,574,208 bf16 (41.1 MB)
  __bf16* convout = poolbuf + 20574208;         // 10,287,104 bf16 (20.6 MB)
  __bf16* wbuf = convout + 10287104;            // 281,088 bf16 (0.56 MB)
  __bf16* W1b = wbuf;                           // 128*1152
  __bf16* W2b = W1b + 147456;                   // 64*1152
  __bf16* W3b = W2b + 73728;                    // 64*576
  __bf16* W4b = W3b + 36864;                    // 32*576
  __bf16* Wfp = W4b + 18432;                    // 16*288 zero-padded
  int* csr = (int*)(wbuf + 281088);
  int* cnt0 = csr;            int* cnt1 = cnt0 + N0;   int* cnt2 = cnt1 + N1;   int* cnt3 = cnt2 + N2;
  int* off0 = csr + 6672;     int* off1 = off0 + N0+1; int* off2 = off1 + N1+1; int* off3 = off2 + N2+1;
  int* cur0 = csr + 13348;    int* cur1 = cur0 + N0;   int* cur2 = cur1 + N1;   int* cur3 = cur2 + N2;
  int2* pk0 = (int2*)(csr + 20020);             // 8B aligned
  int2* pk1 = pk0 + NNZ0;
  int2* pk2 = pk1 + NNZ1;
  int2* pk3 = pk2 + NNZ2;

  // ---- CSR build ----
  hipMemsetAsync(cnt0, 0, 6672 * sizeof(int), stream);
  csr_count_kernel<<<(20016 + 255) / 256, 256, 0, stream>>>(
      up0_rows, up1_rows, up2_rows, up3_rows, cnt0, cnt1, cnt2, cnt3);
  csr_scan_kernel<<<4, 256, 0, stream>>>(cnt0, cnt1, cnt2, cnt3,
                                         off0, off1, off2, off3,
                                         cur0, cur1, cur2, cur3);
  csr_bucket_kernel<<<(20016 + 255) / 256, 256, 0, stream>>>(
      up0_rows, up1_rows, up2_rows, up3_rows,
      up0_cols, up1_cols, up2_cols, up3_cols,
      up0_vals, up1_vals, up2_vals, up3_vals,
      cur0, cur1, cur2, cur3, pk0, pk1, pk2, pk3);

  // ---- weights -> bf16 ----
  cvt_all_kernel<<<(281088 + 255) / 256, 256, 0, stream>>>(W1, W2, W3, W4, Wf, wbuf);

  // ---- dense: latent -> [20][64][128] bf16 (vt-major) ----
  linear0_kernel<<<(64 * 2560 + 255) / 256, 256, 0, stream>>>(latent, W0, b0, convout);

  // ---- level 3: pool 20->79 (C=128), conv 128->128 (WV=1: 316 blocks) ----
  pool_csr_kernel<128, 16><<<(N3 * 4 * 128 + 255) / 256, 256, 0, stream>>>(
      convout, off3, pk3, poolbuf, N3);
  conv_mfma_kernel<128, 128, 1><<<dim3(N3, 4), 64, 0, stream>>>(
      poolbuf, spiral3, W1b, b1, convout);

  // ---- level 2: pool 79->314 (C=128), conv 128->64 (WV=1: 1256 blocks) ----
  pool_csr_kernel<128, 16><<<(N2 * 4 * 128 + 255) / 256, 256, 0, stream>>>(
      convout, off2, pk2, poolbuf, N2);
  conv_mfma_kernel<128, 64, 1><<<dim3(N2, 4), 64, 0, stream>>>(
      poolbuf, spiral2, W2b, b2, convout);

  // ---- level 1: pool 314->1256 (C=64), conv 64->64 (WV=4: block = v) ----
  pool_csr_kernel<64, 16><<<(N1 * 4 * 64 + 255) / 256, 256, 0, stream>>>(
      convout, off1, pk1, poolbuf, N1);
  conv_mfma_kernel<64, 64, 4><<<dim3(N1, 1), 256, 0, stream>>>(
      poolbuf, spiral1, W3b, b3, convout);

  // ---- level 0: pool 1256->5023 (C=64), conv 64->32 (WV=4: block = v) ----
  pool_csr_kernel<64, 16><<<(N0 * 4 * 64 + 255) / 256, 256, 0, stream>>>(
      convout, off0, pk0, poolbuf, N0);
  conv_mfma_kernel<64, 32, 4><<<dim3(N0, 1), 256, 0, stream>>>(
      poolbuf, spiral0, W4b, b4, convout);

  // ---- final conv 32->3 + actor ([t][v][3] output) ----
  final_mfma_kernel<<<N0, 256, 0, stream>>>(convout, spiral0, Wfp, bf3, actor, out);
}

// Round 7
// 406.237 us; speedup vs baseline: 6.8896x; 1.1282x over previous
//
#include <hip/hip_runtime.h>
#include <hip/hip_bf16.h>

#define T_FRAMES 64

typedef __bf16 bf16x8 __attribute__((ext_vector_type(8)));
typedef float f32x4 __attribute__((ext_vector_type(4)));

// edge counts per level (fine->coarse): nnz = 3 * n_fine
#define NNZ0 15069
#define NNZ1 3768
#define NNZ2 942
#define NNZ3 237
#define N0 5023
#define N1 1256
#define N2 314
#define N3 79
#define N4 20

// All activation buffers are vt-major: [vert][t][C]. d_out stays [t][v][3].

// ---------------------------------------------------------------------------
// de_layers[0] -> vt-major bf16
// ---------------------------------------------------------------------------
__global__ __launch_bounds__(256) void linear0_kernel(
    const float* __restrict__ latent, const float* __restrict__ W0,
    const float* __restrict__ b0, __bf16* __restrict__ out) {
  int id = blockIdx.x * 256 + threadIdx.x;
  if (id >= 64 * 2560) return;
  int j = id % 2560;
  int t = id / 2560;
  const float* lrow = latent + t * 128;
  const float* wrow = W0 + j * 128;
  float acc = b0[j];
#pragma unroll 8
  for (int k = 0; k < 128; ++k) acc = fmaf(lrow[k], wrow[k], acc);
  out[((size_t)(j >> 7) * 64 + t) * 128 + (j & 127)] = (__bf16)acc;
}

// ---------------------------------------------------------------------------
// all weights fp32 -> bf16 (Wf zero-padded 3x288 -> 16x288)
// ---------------------------------------------------------------------------
__global__ __launch_bounds__(256) void cvt_all_kernel(
    const float* __restrict__ W1, const float* __restrict__ W2,
    const float* __restrict__ W3, const float* __restrict__ W4,
    const float* __restrict__ Wf, __bf16* __restrict__ o) {
  int i = blockIdx.x * 256 + threadIdx.x;
  if (i < 147456) { o[i] = (__bf16)W1[i]; return; }
  if (i < 221184) { o[i] = (__bf16)W2[i - 147456]; return; }
  if (i < 258048) { o[i] = (__bf16)W3[i - 221184]; return; }
  if (i < 276480) { o[i] = (__bf16)W4[i - 258048]; return; }
  if (i < 281088) {
    int j = i - 276480;
    o[i] = (j / 288 < 3) ? (__bf16)Wf[j] : (__bf16)0.f;
  }
}

// ---------------------------------------------------------------------------
// CSR build: count -> scan -> packed bucket fill ({col, val_bits})
// ---------------------------------------------------------------------------
__global__ __launch_bounds__(256) void csr_count_kernel(
    const int* __restrict__ r0, const int* __restrict__ r1,
    const int* __restrict__ r2, const int* __restrict__ r3,
    int* __restrict__ c0, int* __restrict__ c1,
    int* __restrict__ c2, int* __restrict__ c3) {
  int i = blockIdx.x * 256 + threadIdx.x;
  if (i < NNZ0) atomicAdd(&c0[r0[i]], 1);
  else if (i < NNZ0 + NNZ1) atomicAdd(&c1[r1[i - NNZ0]], 1);
  else if (i < NNZ0 + NNZ1 + NNZ2) atomicAdd(&c2[r2[i - NNZ0 - NNZ1]], 1);
  else if (i < NNZ0 + NNZ1 + NNZ2 + NNZ3) atomicAdd(&c3[r3[i - NNZ0 - NNZ1 - NNZ2]], 1);
}

__global__ __launch_bounds__(256) void csr_scan_kernel(
    const int* __restrict__ c0, const int* __restrict__ c1,
    const int* __restrict__ c2, const int* __restrict__ c3,
    int* __restrict__ o0, int* __restrict__ o1,
    int* __restrict__ o2, int* __restrict__ o3,
    int* __restrict__ u0, int* __restrict__ u1,
    int* __restrict__ u2, int* __restrict__ u3) {
  const int b = blockIdx.x;
  const int* counts = b == 0 ? c0 : b == 1 ? c1 : b == 2 ? c2 : c3;
  int* off = b == 0 ? o0 : b == 1 ? o1 : b == 2 ? o2 : o3;
  int* cur = b == 0 ? u0 : b == 1 ? u1 : b == 2 ? u2 : u3;
  const int n = b == 0 ? N0 : b == 1 ? N1 : b == 2 ? N2 : N3;

  __shared__ int part[256];
  const int chunk = (n + 255) / 256;
  const int start = threadIdx.x * chunk;
  const int end = min(start + chunk, n);
  int s = 0;
  for (int i = start; i < end; ++i) s += counts[i];
  part[threadIdx.x] = s;
  __syncthreads();
  for (int d = 1; d < 256; d <<= 1) {
    int v = (threadIdx.x >= d) ? part[threadIdx.x - d] : 0;
    __syncthreads();
    part[threadIdx.x] += v;
    __syncthreads();
  }
  int run = (threadIdx.x == 0) ? 0 : part[threadIdx.x - 1];
  for (int i = start; i < end; ++i) {
    off[i] = run;
    cur[i] = run;
    run += counts[i];
  }
  if (threadIdx.x == 255) off[n] = run;
}

__global__ __launch_bounds__(256) void csr_bucket_kernel(
    const int* __restrict__ r0, const int* __restrict__ r1,
    const int* __restrict__ r2, const int* __restrict__ r3,
    const int* __restrict__ q0, const int* __restrict__ q1,
    const int* __restrict__ q2, const int* __restrict__ q3,
    const float* __restrict__ v0, const float* __restrict__ v1,
    const float* __restrict__ v2, const float* __restrict__ v3,
    int* __restrict__ u0, int* __restrict__ u1,
    int* __restrict__ u2, int* __restrict__ u3,
    int2* __restrict__ p0, int2* __restrict__ p1,
    int2* __restrict__ p2, int2* __restrict__ p3) {
  int i = blockIdx.x * 256 + threadIdx.x;
  if (i < NNZ0) {
    int p = atomicAdd(&u0[r0[i]], 1);
    p0[p] = make_int2(q0[i], __float_as_int(v0[i]));
  } else if (i < NNZ0 + NNZ1) {
    int e = i - NNZ0;
    int p = atomicAdd(&u1[r1[e]], 1);
    p1[p] = make_int2(q1[e], __float_as_int(v1[e]));
  } else if (i < NNZ0 + NNZ1 + NNZ2) {
    int e = i - NNZ0 - NNZ1;
    int p = atomicAdd(&u2[r2[e]], 1);
    p2[p] = make_int2(q2[e], __float_as_int(v2[e]));
  } else if (i < NNZ0 + NNZ1 + NNZ2 + NNZ3) {
    int e = i - NNZ0 - NNZ1 - NNZ2;
    int p = atomicAdd(&u3[r3[e]], 1);
    p3[p] = make_int2(q3[e], __float_as_int(v3[e]));
  }
}

// ---------------------------------------------------------------------------
// CSR gather pool, vt-major (unchanged from R5 — not a top dispatch)
// ---------------------------------------------------------------------------
template <int C, int TT>
__global__ __launch_bounds__(256) void pool_csr_kernel(
    const __bf16* __restrict__ x, const int* __restrict__ off,
    const int2* __restrict__ pk, __bf16* __restrict__ out, int n_out) {
  unsigned id = blockIdx.x * 256u + threadIdx.x;
  unsigned total = (unsigned)n_out * (T_FRAMES / TT) * C;
  if (id >= total) return;
  const int c = id % C;
  const unsigned rt = id / C;
  const int tb = rt % (T_FRAMES / TT);
  const int row = rt / (T_FRAMES / TT);

  const int o0 = off[row], o1 = off[row + 1];
  float acc[TT];
#pragma unroll
  for (int u = 0; u < TT; ++u) acc[u] = 0.f;

  for (int j = o0; j < o1; ++j) {
    const int2 rec = pk[j];
    const float val = __int_as_float(rec.y);
    const __bf16* xp = x + ((size_t)rec.x * T_FRAMES + tb * TT) * C + c;
#pragma unroll
    for (int u = 0; u < TT; ++u)
      acc[u] = fmaf(val, (float)xp[(size_t)u * C], acc[u]);
  }

  __bf16* op = out + ((size_t)row * T_FRAMES + tb * TT) * C + c;
#pragma unroll
  for (int u = 0; u < TT; ++u) op[(size_t)u * C] = (__bf16)acc[u];
}

// ---------------------------------------------------------------------------
// spiral conv MFMA, vt-major, TWO-PHASE:
//   phase 1: prefetch ALL A-fragments (MT m-tiles x KK) into registers
//            (independent loads -> one latency exposure, deep ILP)
//   phase 2: W-load + MFMA loop (W small, L2-resident, reused by all blocks)
// Block = one vertex slice: WV waves, wave w covers m-tiles (by*WV+w)*MT ..
// ---------------------------------------------------------------------------
template <int CIN, int COUT, int WV, int MT>
__global__ __launch_bounds__(256) void conv_mfma_kernel(
    const __bf16* __restrict__ x, const int* __restrict__ idx,
    const __bf16* __restrict__ Wb, const float* __restrict__ bias,
    __bf16* __restrict__ out) {
  constexpr int K = 9 * CIN;
  constexpr int KK = K / 32;
  constexpr int NT = COUT / 16;

  const int lane = threadIdx.x & 63;
  const int wid = threadIdx.x >> 6;
  const int v = blockIdx.x;
  const int tq0 = (blockIdx.y * WV + wid) * MT;   // first t-tile (16 rows each)
  const int col = lane & 15;
  const int kg = lane >> 4;

  size_t vbase[9];                                 // block-uniform spiral gather
#pragma unroll
  for (int s = 0; s < 9; ++s)
    vbase[s] = (size_t)idx[v * 9 + s] * (T_FRAMES * CIN);

  // ---- phase 1: prefetch all A fragments ----
  bf16x8 a[MT][KK];
#pragma unroll
  for (int mt = 0; mt < MT; ++mt) {
    const size_t trow = (size_t)(tq0 + mt) * 16 + col;
#pragma unroll
    for (int kk = 0; kk < KK; ++kk) {
      const int s = (kk * 32) / CIN;     // constants under unroll
      const int ci0 = (kk * 32) % CIN;
      a[mt][kk] = *(const bf16x8*)(x + vbase[s] + trow * CIN + ci0 + kg * 8);
    }
  }

  f32x4 acc[MT][NT];
#pragma unroll
  for (int nt = 0; nt < NT; ++nt) {
    float b = bias[nt * 16 + col];
#pragma unroll
    for (int mt = 0; mt < MT; ++mt) acc[mt][nt] = (f32x4){b, b, b, b};
  }

  // ---- phase 2: W loads + MFMA ----
#pragma unroll
  for (int kk = 0; kk < KK; ++kk) {
#pragma unroll
    for (int nt = 0; nt < NT; ++nt) {
      bf16x8 bfr = *(const bf16x8*)(Wb + (size_t)(nt * 16 + col) * K + kk * 32 + kg * 8);
#pragma unroll
      for (int mt = 0; mt < MT; ++mt)
        acc[mt][nt] = __builtin_amdgcn_mfma_f32_16x16x32_bf16(a[mt][kk], bfr, acc[mt][nt], 0, 0, 0);
    }
  }

  // ---- store (D: col=channel, row kg*4+j = t within tile), ELU, vt-major ----
#pragma unroll
  for (int mt = 0; mt < MT; ++mt) {
#pragma unroll
    for (int j = 0; j < 4; ++j) {
      const size_t tr = (size_t)(tq0 + mt) * 16 + kg * 4 + j;
#pragma unroll
      for (int nt = 0; nt < NT; ++nt) {
        float aa = acc[mt][nt][j];
        aa = aa > 0.f ? aa : expm1f(aa);   // ELU
        out[((size_t)v * T_FRAMES + tr) * COUT + nt * 16 + col] = (__bf16)aa;
      }
    }
  }
}

// ---------------------------------------------------------------------------
// final conv 32->3 (+actor), two-phase prefetch, [t][v][3] output.
// ---------------------------------------------------------------------------
__global__ __launch_bounds__(256) void final_mfma_kernel(
    const __bf16* __restrict__ x, const int* __restrict__ idx,
    const __bf16* __restrict__ Wfp, const float* __restrict__ bf3,
    const float* __restrict__ actor, float* __restrict__ out) {
  const int lane = threadIdx.x & 63;
  const int wid = threadIdx.x >> 6;
  const int v = blockIdx.x;
  const int col = lane & 15;
  const int kg = lane >> 4;
  const size_t trow = (size_t)wid * 16 + col;

  bf16x8 a[9];
#pragma unroll
  for (int s = 0; s < 9; ++s)
    a[s] = *(const bf16x8*)(x + (size_t)idx[v * 9 + s] * (T_FRAMES * 32) + trow * 32 + kg * 8);

  float b = (col < 3) ? bf3[col] : 0.f;
  f32x4 acc = (f32x4){b, b, b, b};

#pragma unroll
  for (int kk = 0; kk < 9; ++kk) {
    bf16x8 w = *(const bf16x8*)(Wfp + col * 288 + kk * 32 + kg * 8);
    acc = __builtin_amdgcn_mfma_f32_16x16x32_bf16(a[kk], w, acc, 0, 0, 0);
  }

  if (col < 3) {
    const float av = actor[v * 3 + col];
#pragma unroll
    for (int j = 0; j < 4; ++j) {
      const int tr = wid * 16 + kg * 4 + j;
      out[((size_t)tr * N0 + v) * 3 + col] = acc[j] + av;
    }
  }
}

// ---------------------------------------------------------------------------
extern "C" void kernel_launch(void* const* d_in, const int* in_sizes, int n_in_args,
                              void* d_out, int out_size, void* d_ws, size_t ws_size,
                              hipStream_t stream) {
  const float* latent = (const float*)d_in[0];
  const float* actor  = (const float*)d_in[1];
  const int* spiral0 = (const int*)d_in[2];
  const int* spiral1 = (const int*)d_in[3];
  const int* spiral2 = (const int*)d_in[4];
  const int* spiral3 = (const int*)d_in[5];
  const int* up0_rows = (const int*)d_in[6];
  const int* up0_cols = (const int*)d_in[7];
  const float* up0_vals = (const float*)d_in[8];
  const int* up1_rows = (const int*)d_in[9];
  const int* up1_cols = (const int*)d_in[10];
  const float* up1_vals = (const float*)d_in[11];
  const int* up2_rows = (const int*)d_in[12];
  const int* up2_cols = (const int*)d_in[13];
  const float* up2_vals = (const float*)d_in[14];
  const int* up3_rows = (const int*)d_in[15];
  const int* up3_cols = (const int*)d_in[16];
  const float* up3_vals = (const float*)d_in[17];
  const float* W0 = (const float*)d_in[18];
  const float* b0 = (const float*)d_in[19];
  const float* W1 = (const float*)d_in[20];
  const float* b1 = (const float*)d_in[21];
  const float* W2 = (const float*)d_in[22];
  const float* b2 = (const float*)d_in[23];
  const float* W3 = (const float*)d_in[24];
  const float* b3 = (const float*)d_in[25];
  const float* W4 = (const float*)d_in[26];
  const float* b4 = (const float*)d_in[27];
  const float* Wf = (const float*)d_in[28];
  const float* bf3 = (const float*)d_in[29];
  float* out = (float*)d_out;

  // ---- workspace layout (~62.5 MB) ----
  __bf16* poolbuf = (__bf16*)d_ws;              // 20,574,208 bf16 (41.1 MB)
  __bf16* convout = poolbuf + 20574208;         // 10,287,104 bf16 (20.6 MB)
  __bf16* wbuf = convout + 10287104;            // 281,088 bf16 (0.56 MB)
  __bf16* W1b = wbuf;                           // 128*1152
  __bf16* W2b = W1b + 147456;                   // 64*1152
  __bf16* W3b = W2b + 73728;                    // 64*576
  __bf16* W4b = W3b + 36864;                    // 32*576
  __bf16* Wfp = W4b + 18432;                    // 16*288 zero-padded
  int* csr = (int*)(wbuf + 281088);
  int* cnt0 = csr;            int* cnt1 = cnt0 + N0;   int* cnt2 = cnt1 + N1;   int* cnt3 = cnt2 + N2;
  int* off0 = csr + 6672;     int* off1 = off0 + N0+1; int* off2 = off1 + N1+1; int* off3 = off2 + N2+1;
  int* cur0 = csr + 13348;    int* cur1 = cur0 + N0;   int* cur2 = cur1 + N1;   int* cur3 = cur2 + N2;
  int2* pk0 = (int2*)(csr + 20020);             // 8B aligned
  int2* pk1 = pk0 + NNZ0;
  int2* pk2 = pk1 + NNZ1;
  int2* pk3 = pk2 + NNZ2;

  // ---- CSR build ----
  hipMemsetAsync(cnt0, 0, 6672 * sizeof(int), stream);
  csr_count_kernel<<<(20016 + 255) / 256, 256, 0, stream>>>(
      up0_rows, up1_rows, up2_rows, up3_rows, cnt0, cnt1, cnt2, cnt3);
  csr_scan_kernel<<<4, 256, 0, stream>>>(cnt0, cnt1, cnt2, cnt3,
                                         off0, off1, off2, off3,
                                         cur0, cur1, cur2, cur3);
  csr_bucket_kernel<<<(20016 + 255) / 256, 256, 0, stream>>>(
      up0_rows, up1_rows, up2_rows, up3_rows,
      up0_cols, up1_cols, up2_cols, up3_cols,
      up0_vals, up1_vals, up2_vals, up3_vals,
      cur0, cur1, cur2, cur3, pk0, pk1, pk2, pk3);

  // ---- weights -> bf16 ----
  cvt_all_kernel<<<(281088 + 255) / 256, 256, 0, stream>>>(W1, W2, W3, W4, Wf, wbuf);

  // ---- dense: latent -> [20][64][128] bf16 (vt-major) ----
  linear0_kernel<<<(64 * 2560 + 255) / 256, 256, 0, stream>>>(latent, W0, b0, convout);

  // ---- level 3: pool 20->79 (C=128), conv 128->128 (WV=1,MT=1: 316 blocks) ----
  pool_csr_kernel<128, 16><<<(N3 * 4 * 128 + 255) / 256, 256, 0, stream>>>(
      convout, off3, pk3, poolbuf, N3);
  conv_mfma_kernel<128, 128, 1, 1><<<dim3(N3, 4), 64, 0, stream>>>(
      poolbuf, spiral3, W1b, b1, convout);

  // ---- level 2: pool 79->314 (C=128), conv 128->64 (WV=1,MT=1: 1256 blocks) ----
  pool_csr_kernel<128, 16><<<(N2 * 4 * 128 + 255) / 256, 256, 0, stream>>>(
      convout, off2, pk2, poolbuf, N2);
  conv_mfma_kernel<128, 64, 1, 1><<<dim3(N2, 4), 64, 0, stream>>>(
      poolbuf, spiral2, W2b, b2, convout);

  // ---- level 1: pool 314->1256 (C=64), conv 64->64 (WV=2,MT=2) ----
  pool_csr_kernel<64, 16><<<(N1 * 4 * 64 + 255) / 256, 256, 0, stream>>>(
      convout, off1, pk1, poolbuf, N1);
  conv_mfma_kernel<64, 64, 2, 2><<<dim3(N1, 1), 128, 0, stream>>>(
      poolbuf, spiral1, W3b, b3, convout);

  // ---- level 0: pool 1256->5023 (C=64), conv 64->32 (WV=2,MT=2) ----
  pool_csr_kernel<64, 16><<<(N0 * 4 * 64 + 255) / 256, 256, 0, stream>>>(
      convout, off0, pk0, poolbuf, N0);
  conv_mfma_kernel<64, 32, 2, 2><<<dim3(N0, 1), 128, 0, stream>>>(
      poolbuf, spiral0, W4b, b4, convout);

  // ---- final conv 32->3 + actor ([t][v][3] output) ----
  final_mfma_kernel<<<N0, 256, 0, stream>>>(convout, spiral0, Wfp, bf3, actor, out);
}